// Round 1
// baseline (1031.053 us; speedup 1.0000x reference)
//
#include <hip/hip_runtime.h>

#define N_NODES 100000
#define N_EDGES 3200000
#define IN_CH 24
#define HIDDEN 64
#define N_CLASSES 16

// ---------------- CSR build ----------------

__global__ __launch_bounds__(256) void k_hist(const int* __restrict__ dst,
                                              int* __restrict__ cnt, int E) {
    int e = blockIdx.x * blockDim.x + threadIdx.x;
    if (e < E) atomicAdd(&cnt[dst[e]], 1);
}

// single-block exclusive scan of cnt[N] -> rowptr[N+1], plus rowfill copy
__global__ __launch_bounds__(1024) void k_scan(const int* __restrict__ cnt,
                                               int* __restrict__ rowptr,
                                               int* __restrict__ rowfill,
                                               int N, int E) {
    __shared__ int lds[1024];
    int t = threadIdx.x;
    int chunk = (N + 1023) / 1024;
    int beg = t * chunk;
    int end = min(beg + chunk, N);
    int s = 0;
    for (int i = beg; i < end; i++) s += cnt[i];
    lds[t] = s;
    __syncthreads();
    int val = s;
    for (int off = 1; off < 1024; off <<= 1) {
        int v = (t >= off) ? lds[t - off] : 0;
        __syncthreads();
        val += v;
        lds[t] = val;
        __syncthreads();
    }
    int run = val - s;  // exclusive prefix
    for (int i = beg; i < end; i++) {
        rowptr[i] = run;
        rowfill[i] = run;
        run += cnt[i];
    }
    if (end == N && beg <= N) rowptr[N] = E;
}

__global__ __launch_bounds__(256) void k_fill(const int* __restrict__ src,
                                              const int* __restrict__ dst,
                                              int* __restrict__ rowfill,
                                              int* __restrict__ srcs, int E) {
    int e = blockIdx.x * blockDim.x + threadIdx.x;
    if (e < E) {
        int d = dst[e];
        int p = atomicAdd(&rowfill[d], 1);
        srcs[p] = src[e];
    }
}

// ---------------- layer 1 ----------------

// 32 threads per node, lanes 0..23 own one input channel each
__global__ __launch_bounds__(256) void k_agg1(const float* __restrict__ x,
                                              const int* __restrict__ rowptr,
                                              const int* __restrict__ srcs,
                                              float* __restrict__ mean1, int N) {
    int gid = blockIdx.x * blockDim.x + threadIdx.x;
    int node = gid >> 5;
    int lane = gid & 31;
    if (node >= N || lane >= IN_CH) return;
    int b = rowptr[node], e = rowptr[node + 1];
    float s0 = 0.f, s1 = 0.f, s2 = 0.f, s3 = 0.f;
    int j = b;
    for (; j + 3 < e; j += 4) {
        int a0 = srcs[j], a1 = srcs[j + 1], a2 = srcs[j + 2], a3 = srcs[j + 3];
        s0 += x[a0 * IN_CH + lane];
        s1 += x[a1 * IN_CH + lane];
        s2 += x[a2 * IN_CH + lane];
        s3 += x[a3 * IN_CH + lane];
    }
    for (; j < e; j++) s0 += x[srcs[j] * IN_CH + lane];
    float s = (s0 + s1) + (s2 + s3);
    float d = (float)max(e - b, 1);
    mean1[node * IN_CH + lane] = s / d;
}

// h = relu(mean1 @ W1l^T + b1 + x @ W1r^T); 4 nodes x 64 out-ch per tile
__global__ __launch_bounds__(256) void k_xform1(const float* __restrict__ x,
                                                const float* __restrict__ mean1,
                                                const float* __restrict__ W1l,
                                                const float* __restrict__ b1,
                                                const float* __restrict__ W1r,
                                                float* __restrict__ h, int N) {
    __shared__ float WlT[IN_CH][HIDDEN];
    __shared__ float WrT[IN_CH][HIDDEN];
    __shared__ float bs[HIDDEN];
    __shared__ float xs[4][IN_CH];
    __shared__ float ms[4][IN_CH];
    int t = threadIdx.x;
    for (int i = t; i < HIDDEN * IN_CH; i += 256) {
        int o = i / IN_CH, k = i % IN_CH;
        WlT[k][o] = W1l[i];
        WrT[k][o] = W1r[i];
    }
    if (t < HIDDEN) bs[t] = b1[t];
    int ntiles = (N + 3) / 4;
    for (int tile = blockIdx.x; tile < ntiles; tile += gridDim.x) {
        int base = tile * 4;
        __syncthreads();
        if (t < 4 * IN_CH) {
            int n = t / IN_CH, k = t % IN_CH;
            int node = base + n;
            if (node < N) {
                xs[n][k] = x[node * IN_CH + k];
                ms[n][k] = mean1[node * IN_CH + k];
            }
        }
        __syncthreads();
        int n = t >> 6, o = t & 63;
        int node = base + n;
        if (node < N) {
            float acc = bs[o];
#pragma unroll
            for (int k = 0; k < IN_CH; k++)
                acc += WlT[k][o] * ms[n][k] + WrT[k][o] * xs[n][k];
            h[node * HIDDEN + o] = fmaxf(acc, 0.f);
        }
    }
}

// ---------------- layer 2 ----------------

// 64 threads per node, one lane per hidden channel
__global__ __launch_bounds__(256) void k_agg2(const float* __restrict__ h,
                                              const int* __restrict__ rowptr,
                                              const int* __restrict__ srcs,
                                              float* __restrict__ mean2, int N) {
    int gid = blockIdx.x * blockDim.x + threadIdx.x;
    int node = gid >> 6;
    int lane = gid & 63;
    if (node >= N) return;
    int b = rowptr[node], e = rowptr[node + 1];
    float s0 = 0.f, s1 = 0.f, s2 = 0.f, s3 = 0.f;
    int j = b;
    for (; j + 3 < e; j += 4) {
        int a0 = srcs[j], a1 = srcs[j + 1], a2 = srcs[j + 2], a3 = srcs[j + 3];
        s0 += h[a0 * HIDDEN + lane];
        s1 += h[a1 * HIDDEN + lane];
        s2 += h[a2 * HIDDEN + lane];
        s3 += h[a3 * HIDDEN + lane];
    }
    for (; j < e; j++) s0 += h[srcs[j] * HIDDEN + lane];
    float s = (s0 + s1) + (s2 + s3);
    mean2[node * HIDDEN + lane] = s / (float)max(e - b, 1);
}

// emb = mean2 @ W2l^T + b2 + h @ W2r^T ; logits = emb @ Wc^T + bc
// mean2 aliases emb region in d_out: staged to LDS before overwrite.
__global__ __launch_bounds__(256) void k_xform2(const float* __restrict__ h,
                                                const float* __restrict__ mean2,
                                                const float* __restrict__ W2l,
                                                const float* __restrict__ b2,
                                                const float* __restrict__ W2r,
                                                const float* __restrict__ Wc,
                                                const float* __restrict__ bc,
                                                float* __restrict__ logits,
                                                float* __restrict__ emb, int N) {
    __shared__ float WlT[HIDDEN][HIDDEN + 1];
    __shared__ float WrT[HIDDEN][HIDDEN + 1];
    __shared__ float WcT[HIDDEN][N_CLASSES];
    __shared__ float b2s[HIDDEN];
    __shared__ float bcs[N_CLASSES];
    __shared__ float hs[4][HIDDEN];
    __shared__ float m2s[4][HIDDEN];
    __shared__ float es[4][HIDDEN];
    int t = threadIdx.x;
    for (int i = t; i < HIDDEN * HIDDEN; i += 256) {
        int o = i >> 6, k = i & 63;
        WlT[k][o] = W2l[i];
        WrT[k][o] = W2r[i];
    }
    for (int i = t; i < N_CLASSES * HIDDEN; i += 256) {
        int c = i >> 6, k = i & 63;
        WcT[k][c] = Wc[i];
    }
    if (t < HIDDEN) b2s[t] = b2[t];
    if (t < N_CLASSES) bcs[t] = bc[t];
    int ntiles = (N + 3) / 4;
    for (int tile = blockIdx.x; tile < ntiles; tile += gridDim.x) {
        int base = tile * 4;
        __syncthreads();
        {
            int n = t >> 6, k = t & 63;
            int node = base + n;
            if (node < N) {
                hs[n][k] = h[node * HIDDEN + k];
                m2s[n][k] = mean2[node * HIDDEN + k];
            }
        }
        __syncthreads();
        int n = t >> 6, o = t & 63;
        int node = base + n;
        if (node < N) {
            float acc = b2s[o];
#pragma unroll 8
            for (int k = 0; k < HIDDEN; k++)
                acc += WlT[k][o] * m2s[n][k] + WrT[k][o] * hs[n][k];
            es[n][o] = acc;
            emb[node * HIDDEN + o] = acc;
        }
        __syncthreads();
        if (t < 4 * N_CLASSES) {
            int nn = t >> 4, c = t & 15;
            int node2 = base + nn;
            if (node2 < N) {
                float a = bcs[c];
#pragma unroll 8
                for (int k = 0; k < HIDDEN; k++) a += WcT[k][c] * es[nn][k];
                logits[node2 * N_CLASSES + c] = a;
            }
        }
    }
}

// ---------------- launch ----------------

extern "C" void kernel_launch(void* const* d_in, const int* in_sizes, int n_in,
                              void* d_out, int out_size, void* d_ws, size_t ws_size,
                              hipStream_t stream) {
    const float* x = (const float*)d_in[0];
    const int* edge = (const int*)d_in[1];
    const int* srcIdx = edge;
    const int* dstIdx = edge + N_EDGES;
    const float* W1l = (const float*)d_in[2];
    const float* b1  = (const float*)d_in[3];
    const float* W1r = (const float*)d_in[4];
    const float* W2l = (const float*)d_in[5];
    const float* b2  = (const float*)d_in[6];
    const float* W2r = (const float*)d_in[7];
    const float* Wc  = (const float*)d_in[8];
    const float* bc  = (const float*)d_in[9];

    float* logits = (float*)d_out;
    float* emb = (float*)d_out + (size_t)N_NODES * N_CLASSES;

    // workspace carve-up (256B aligned)
    char* w = (char*)d_ws;
    auto carve = [&](size_t bytes) {
        char* p = w;
        w += (bytes + 255) & ~(size_t)255;
        return p;
    };
    int* rowptr  = (int*)carve((N_NODES + 1) * sizeof(int));
    int* cnt     = (int*)carve(N_NODES * sizeof(int));
    int* rowfill = (int*)carve(N_NODES * sizeof(int));
    int* srcs    = (int*)carve((size_t)N_EDGES * sizeof(int));
    float* h     = (float*)carve((size_t)N_NODES * HIDDEN * sizeof(float));

    // mean buffers alias the emb output region (dead until k_xform2 rewrites it)
    float* mean1 = emb;  // N x 24 fits in N x 64
    float* mean2 = emb;  // N x 64

    hipMemsetAsync(cnt, 0, N_NODES * sizeof(int), stream);

    int ebl = (N_EDGES + 255) / 256;
    k_hist<<<ebl, 256, 0, stream>>>(dstIdx, cnt, N_EDGES);
    k_scan<<<1, 1024, 0, stream>>>(cnt, rowptr, rowfill, N_NODES, N_EDGES);
    k_fill<<<ebl, 256, 0, stream>>>(srcIdx, dstIdx, rowfill, srcs, N_EDGES);

    int a1bl = (N_NODES * 32 + 255) / 256;
    k_agg1<<<a1bl, 256, 0, stream>>>(x, rowptr, srcs, mean1, N_NODES);
    k_xform1<<<1024, 256, 0, stream>>>(x, mean1, W1l, b1, W1r, h, N_NODES);

    int a2bl = (N_NODES * 64 + 255) / 256;
    k_agg2<<<a2bl, 256, 0, stream>>>(h, rowptr, srcs, mean2, N_NODES);
    k_xform2<<<1024, 256, 0, stream>>>(h, mean2, W2l, b2, W2r, Wc, bc,
                                       logits, emb, N_NODES);
}

// Round 2
// 518.529 us; speedup vs baseline: 1.9884x; 1.9884x over previous
//
#include <hip/hip_runtime.h>

#define N_NODES 100000
#define N_EDGES 3200000
#define IN_CH 24
#define HIDDEN 64
#define N_CLASSES 16

#define NBUCK 391      // ceil(N_NODES / 256)
#define CHUNK 8192     // edges per partition block

// ---------------- CSR build (two-level partition) ----------------

// coarse histogram: LDS-binned, ~100K global atomics total
__global__ __launch_bounds__(256) void k_phist(const int* __restrict__ dst,
                                               int* __restrict__ bucketCnt, int E) {
    __shared__ int hist[NBUCK];
    int t = threadIdx.x;
    for (int i = t; i < NBUCK; i += 256) hist[i] = 0;
    __syncthreads();
    for (int e = blockIdx.x * 256 + t; e < E; e += 256 * gridDim.x)
        atomicAdd(&hist[dst[e] >> 8], 1);
    __syncthreads();
    for (int i = t; i < NBUCK; i += 256)
        if (hist[i]) atomicAdd(&bucketCnt[i], hist[i]);
}

// tiny scan over 391 buckets
__global__ __launch_bounds__(512) void k_scanb(const int* __restrict__ bucketCnt,
                                               int* __restrict__ bucketBase,
                                               int* __restrict__ bucketFill, int E) {
    __shared__ int lds[512];
    int t = threadIdx.x;
    int c = (t < NBUCK) ? bucketCnt[t] : 0;
    int val = c;
    lds[t] = val;
    __syncthreads();
    for (int off = 1; off < 512; off <<= 1) {
        int v = (t >= off) ? lds[t - off] : 0;
        __syncthreads();
        val += v;
        lds[t] = val;
        __syncthreads();
    }
    if (t < NBUCK) {
        int ex = val - c;
        bucketBase[t] = ex;
        bucketFill[t] = ex;
    }
    if (t == 0) bucketBase[NBUCK] = E;
}

// partition edges into coarse buckets; writes are ~84B contiguous segments
// per (block,bucket) -> low write amplification
__global__ __launch_bounds__(256) void k_part(const int* __restrict__ src,
                                              const int* __restrict__ dst,
                                              int* __restrict__ bucketFill,
                                              unsigned int* __restrict__ pedges, int E) {
    __shared__ int cntL[NBUCK];
    __shared__ int baseL[NBUCK];
    int t = threadIdx.x;
    int cbeg = blockIdx.x * CHUNK;
    int cend = min(cbeg + CHUNK, E);
    for (int i = t; i < NBUCK; i += 256) cntL[i] = 0;
    __syncthreads();
    for (int j = cbeg + t; j < cend; j += 256)
        atomicAdd(&cntL[dst[j] >> 8], 1);
    __syncthreads();
    for (int i = t; i < NBUCK; i += 256) {
        int c = cntL[i];
        if (c) baseL[i] = atomicAdd(&bucketFill[i], c);
        cntL[i] = 0;
    }
    __syncthreads();
    for (int j = cbeg + t; j < cend; j += 256) {
        int d = dst[j], s = src[j];
        int bk = d >> 8;
        int r = atomicAdd(&cntL[bk], 1);
        pedges[baseL[bk] + r] = ((unsigned int)(d & 255) << 17) | (unsigned int)s;
    }
}

// per-bucket CSR finalize: one block per 256-node bucket, all LDS atomics,
// global writes confined to one ~32KB segment (single XCD L2)
__global__ __launch_bounds__(256) void k_bucket(const unsigned int* __restrict__ pedges,
                                                const int* __restrict__ bucketBase,
                                                int* __restrict__ rowptr,
                                                int* __restrict__ srcs, int N, int E) {
    __shared__ int ncnt[256];
    __shared__ int scanb[256];
    int b = blockIdx.x;
    int t = threadIdx.x;
    int eb = bucketBase[b], ee = bucketBase[b + 1];
    ncnt[t] = 0;
    __syncthreads();
    for (int j = eb + t; j < ee; j += 256) {
        unsigned int v = pedges[j];
        atomicAdd(&ncnt[v >> 17], 1);
    }
    __syncthreads();
    int myc = ncnt[t];
    int val = myc;
    scanb[t] = val;
    __syncthreads();
    for (int off = 1; off < 256; off <<= 1) {
        int v2 = (t >= off) ? scanb[t - off] : 0;
        __syncthreads();
        val += v2;
        scanb[t] = val;
        __syncthreads();
    }
    int mybase = val - myc;  // exclusive
    int node = b * 256 + t;
    if (node < N) rowptr[node] = eb + mybase;
    if (b == 0 && t == 0) rowptr[N] = E;
    // publish per-node base, reset rank counters
    scanb[t] = mybase;
    ncnt[t] = 0;
    __syncthreads();
    for (int j = eb + t; j < ee; j += 256) {
        unsigned int v = pedges[j];
        int nl = v >> 17;
        int r = atomicAdd(&ncnt[nl], 1);
        srcs[eb + scanb[nl] + r] = (int)(v & 0x1FFFF);
    }
}

// ---------------- layer 1 ----------------

__global__ __launch_bounds__(256) void k_agg1(const float* __restrict__ x,
                                              const int* __restrict__ rowptr,
                                              const int* __restrict__ srcs,
                                              float* __restrict__ mean1, int N) {
    int gid = blockIdx.x * blockDim.x + threadIdx.x;
    int node = gid >> 5;
    int lane = gid & 31;
    if (node >= N || lane >= IN_CH) return;
    int b = rowptr[node], e = rowptr[node + 1];
    float s0 = 0.f, s1 = 0.f, s2 = 0.f, s3 = 0.f;
    int j = b;
    for (; j + 3 < e; j += 4) {
        int a0 = srcs[j], a1 = srcs[j + 1], a2 = srcs[j + 2], a3 = srcs[j + 3];
        s0 += x[a0 * IN_CH + lane];
        s1 += x[a1 * IN_CH + lane];
        s2 += x[a2 * IN_CH + lane];
        s3 += x[a3 * IN_CH + lane];
    }
    for (; j < e; j++) s0 += x[srcs[j] * IN_CH + lane];
    float s = (s0 + s1) + (s2 + s3);
    float d = (float)max(e - b, 1);
    mean1[node * IN_CH + lane] = s / d;
}

__global__ __launch_bounds__(256) void k_xform1(const float* __restrict__ x,
                                                const float* __restrict__ mean1,
                                                const float* __restrict__ W1l,
                                                const float* __restrict__ b1,
                                                const float* __restrict__ W1r,
                                                float* __restrict__ h, int N) {
    __shared__ float WlT[IN_CH][HIDDEN];
    __shared__ float WrT[IN_CH][HIDDEN];
    __shared__ float bs[HIDDEN];
    __shared__ float xs[4][IN_CH];
    __shared__ float ms[4][IN_CH];
    int t = threadIdx.x;
    for (int i = t; i < HIDDEN * IN_CH; i += 256) {
        int o = i / IN_CH, k = i % IN_CH;
        WlT[k][o] = W1l[i];
        WrT[k][o] = W1r[i];
    }
    if (t < HIDDEN) bs[t] = b1[t];
    int ntiles = (N + 3) / 4;
    for (int tile = blockIdx.x; tile < ntiles; tile += gridDim.x) {
        int base = tile * 4;
        __syncthreads();
        if (t < 4 * IN_CH) {
            int n = t / IN_CH, k = t % IN_CH;
            int node = base + n;
            if (node < N) {
                xs[n][k] = x[node * IN_CH + k];
                ms[n][k] = mean1[node * IN_CH + k];
            }
        }
        __syncthreads();
        int n = t >> 6, o = t & 63;
        int node = base + n;
        if (node < N) {
            float acc = bs[o];
#pragma unroll
            for (int k = 0; k < IN_CH; k++)
                acc += WlT[k][o] * ms[n][k] + WrT[k][o] * xs[n][k];
            h[node * HIDDEN + o] = fmaxf(acc, 0.f);
        }
    }
}

// ---------------- layer 2 ----------------

__global__ __launch_bounds__(256) void k_agg2(const float* __restrict__ h,
                                              const int* __restrict__ rowptr,
                                              const int* __restrict__ srcs,
                                              float* __restrict__ mean2, int N) {
    int gid = blockIdx.x * blockDim.x + threadIdx.x;
    int node = gid >> 6;
    int lane = gid & 63;
    if (node >= N) return;
    int b = rowptr[node], e = rowptr[node + 1];
    float s0 = 0.f, s1 = 0.f, s2 = 0.f, s3 = 0.f;
    int j = b;
    for (; j + 3 < e; j += 4) {
        int a0 = srcs[j], a1 = srcs[j + 1], a2 = srcs[j + 2], a3 = srcs[j + 3];
        s0 += h[a0 * HIDDEN + lane];
        s1 += h[a1 * HIDDEN + lane];
        s2 += h[a2 * HIDDEN + lane];
        s3 += h[a3 * HIDDEN + lane];
    }
    for (; j < e; j++) s0 += h[srcs[j] * HIDDEN + lane];
    float s = (s0 + s1) + (s2 + s3);
    mean2[node * HIDDEN + lane] = s / (float)max(e - b, 1);
}

__global__ __launch_bounds__(256) void k_xform2(const float* __restrict__ h,
                                                const float* __restrict__ mean2,
                                                const float* __restrict__ W2l,
                                                const float* __restrict__ b2,
                                                const float* __restrict__ W2r,
                                                const float* __restrict__ Wc,
                                                const float* __restrict__ bc,
                                                float* __restrict__ logits,
                                                float* __restrict__ emb, int N) {
    __shared__ float WlT[HIDDEN][HIDDEN + 1];
    __shared__ float WrT[HIDDEN][HIDDEN + 1];
    __shared__ float WcT[HIDDEN][N_CLASSES];
    __shared__ float b2s[HIDDEN];
    __shared__ float bcs[N_CLASSES];
    __shared__ float hs[4][HIDDEN];
    __shared__ float m2s[4][HIDDEN];
    __shared__ float es[4][HIDDEN];
    int t = threadIdx.x;
    for (int i = t; i < HIDDEN * HIDDEN; i += 256) {
        int o = i >> 6, k = i & 63;
        WlT[k][o] = W2l[i];
        WrT[k][o] = W2r[i];
    }
    for (int i = t; i < N_CLASSES * HIDDEN; i += 256) {
        int c = i >> 6, k = i & 63;
        WcT[k][c] = Wc[i];
    }
    if (t < HIDDEN) b2s[t] = b2[t];
    if (t < N_CLASSES) bcs[t] = bc[t];
    int ntiles = (N + 3) / 4;
    for (int tile = blockIdx.x; tile < ntiles; tile += gridDim.x) {
        int base = tile * 4;
        __syncthreads();
        {
            int n = t >> 6, k = t & 63;
            int node = base + n;
            if (node < N) {
                hs[n][k] = h[node * HIDDEN + k];
                m2s[n][k] = mean2[node * HIDDEN + k];
            }
        }
        __syncthreads();
        int n = t >> 6, o = t & 63;
        int node = base + n;
        if (node < N) {
            float acc = b2s[o];
#pragma unroll 8
            for (int k = 0; k < HIDDEN; k++)
                acc += WlT[k][o] * m2s[n][k] + WrT[k][o] * hs[n][k];
            es[n][o] = acc;
            emb[node * HIDDEN + o] = acc;
        }
        __syncthreads();
        if (t < 4 * N_CLASSES) {
            int nn = t >> 4, c = t & 15;
            int node2 = base + nn;
            if (node2 < N) {
                float a = bcs[c];
#pragma unroll 8
                for (int k = 0; k < HIDDEN; k++) a += WcT[k][c] * es[nn][k];
                logits[node2 * N_CLASSES + c] = a;
            }
        }
    }
}

// ---------------- launch ----------------

extern "C" void kernel_launch(void* const* d_in, const int* in_sizes, int n_in,
                              void* d_out, int out_size, void* d_ws, size_t ws_size,
                              hipStream_t stream) {
    const float* x = (const float*)d_in[0];
    const int* edge = (const int*)d_in[1];
    const int* srcIdx = edge;
    const int* dstIdx = edge + N_EDGES;
    const float* W1l = (const float*)d_in[2];
    const float* b1  = (const float*)d_in[3];
    const float* W1r = (const float*)d_in[4];
    const float* W2l = (const float*)d_in[5];
    const float* b2  = (const float*)d_in[6];
    const float* W2r = (const float*)d_in[7];
    const float* Wc  = (const float*)d_in[8];
    const float* bc  = (const float*)d_in[9];

    float* logits = (float*)d_out;
    float* emb = (float*)d_out + (size_t)N_NODES * N_CLASSES;

    char* w = (char*)d_ws;
    auto carve = [&](size_t bytes) {
        char* p = w;
        w += (bytes + 255) & ~(size_t)255;
        return p;
    };
    int* rowptr     = (int*)carve((N_NODES + 1) * sizeof(int));
    int* srcs       = (int*)carve((size_t)N_EDGES * sizeof(int));
    float* h        = (float*)carve((size_t)N_NODES * HIDDEN * sizeof(float));
    int* bucketCnt  = (int*)carve(NBUCK * sizeof(int));
    int* bucketBase = (int*)carve((NBUCK + 1) * sizeof(int));
    int* bucketFill = (int*)carve(NBUCK * sizeof(int));

    // pedges aliases h (dead until k_xform1 writes it, after k_bucket is done)
    unsigned int* pedges = (unsigned int*)h;

    // mean buffers alias the emb output region (dead until k_xform2 rewrites it)
    float* mean1 = emb;
    float* mean2 = emb;

    hipMemsetAsync(bucketCnt, 0, NBUCK * sizeof(int), stream);

    k_phist<<<256, 256, 0, stream>>>(dstIdx, bucketCnt, N_EDGES);
    k_scanb<<<1, 512, 0, stream>>>(bucketCnt, bucketBase, bucketFill, N_EDGES);
    int pbl = (N_EDGES + CHUNK - 1) / CHUNK;
    k_part<<<pbl, 256, 0, stream>>>(srcIdx, dstIdx, bucketFill, pedges, N_EDGES);
    k_bucket<<<NBUCK, 256, 0, stream>>>(pedges, bucketBase, rowptr, srcs,
                                        N_NODES, N_EDGES);

    int a1bl = (N_NODES * 32 + 255) / 256;
    k_agg1<<<a1bl, 256, 0, stream>>>(x, rowptr, srcs, mean1, N_NODES);
    k_xform1<<<1024, 256, 0, stream>>>(x, mean1, W1l, b1, W1r, h, N_NODES);

    int a2bl = (N_NODES * 64 + 255) / 256;
    k_agg2<<<a2bl, 256, 0, stream>>>(h, rowptr, srcs, mean2, N_NODES);
    k_xform2<<<1024, 256, 0, stream>>>(h, mean2, W2l, b2, W2r, Wc, bc,
                                       logits, emb, N_NODES);
}

// Round 3
// 383.117 us; speedup vs baseline: 2.6912x; 1.3534x over previous
//
#include <hip/hip_runtime.h>

#define N_NODES 100000
#define N_EDGES 3200000
#define IN_CH 24
#define HIDDEN 64
#define N_CLASSES 16

#define NBUCK 391      // ceil(N_NODES / 256)
#define CHUNK 8192     // edges per partition block
#define NSTRIPS (N_NODES / 16)   // 6250 exact

typedef __attribute__((ext_vector_type(8))) short short8;
typedef __attribute__((ext_vector_type(4))) float float4_;

__device__ __forceinline__ unsigned short f2bf(float f) {
    union { float f; unsigned int u; } v; v.f = f;
    unsigned int u = v.u;
    return (unsigned short)((u + 0x7FFFu + ((u >> 16) & 1u)) >> 16);
}
__device__ __forceinline__ float bflo(unsigned int u) {
    union { unsigned int u; float f; } v; v.u = u << 16; return v.f;
}
__device__ __forceinline__ float bfhi(unsigned int u) {
    union { unsigned int u; float f; } v; v.u = u & 0xFFFF0000u; return v.f;
}

// ---------------- CSR build (two-level partition, from R1) ----------------

__global__ __launch_bounds__(256) void k_phist(const int* __restrict__ dst,
                                               int* __restrict__ bucketCnt, int E) {
    __shared__ int hist[NBUCK];
    int t = threadIdx.x;
    for (int i = t; i < NBUCK; i += 256) hist[i] = 0;
    __syncthreads();
    for (int e = blockIdx.x * 256 + t; e < E; e += 256 * gridDim.x)
        atomicAdd(&hist[dst[e] >> 8], 1);
    __syncthreads();
    for (int i = t; i < NBUCK; i += 256)
        if (hist[i]) atomicAdd(&bucketCnt[i], hist[i]);
}

__global__ __launch_bounds__(512) void k_scanb(const int* __restrict__ bucketCnt,
                                               int* __restrict__ bucketBase,
                                               int* __restrict__ bucketFill, int E) {
    __shared__ int lds[512];
    int t = threadIdx.x;
    int c = (t < NBUCK) ? bucketCnt[t] : 0;
    int val = c;
    lds[t] = val;
    __syncthreads();
    for (int off = 1; off < 512; off <<= 1) {
        int v = (t >= off) ? lds[t - off] : 0;
        __syncthreads();
        val += v;
        lds[t] = val;
        __syncthreads();
    }
    if (t < NBUCK) {
        int ex = val - c;
        bucketBase[t] = ex;
        bucketFill[t] = ex;
    }
    if (t == 0) bucketBase[NBUCK] = E;
}

__global__ __launch_bounds__(256) void k_part(const int* __restrict__ src,
                                              const int* __restrict__ dst,
                                              int* __restrict__ bucketFill,
                                              unsigned int* __restrict__ pedges, int E) {
    __shared__ int cntL[NBUCK];
    __shared__ int baseL[NBUCK];
    int t = threadIdx.x;
    int cbeg = blockIdx.x * CHUNK;
    int cend = min(cbeg + CHUNK, E);
    for (int i = t; i < NBUCK; i += 256) cntL[i] = 0;
    __syncthreads();
    for (int j = cbeg + t; j < cend; j += 256)
        atomicAdd(&cntL[dst[j] >> 8], 1);
    __syncthreads();
    for (int i = t; i < NBUCK; i += 256) {
        int c = cntL[i];
        if (c) baseL[i] = atomicAdd(&bucketFill[i], c);
        cntL[i] = 0;
    }
    __syncthreads();
    for (int j = cbeg + t; j < cend; j += 256) {
        int d = dst[j], s = src[j];
        int bk = d >> 8;
        int r = atomicAdd(&cntL[bk], 1);
        pedges[baseL[bk] + r] = ((unsigned int)(d & 255) << 17) | (unsigned int)s;
    }
}

__global__ __launch_bounds__(256) void k_bucket(const unsigned int* __restrict__ pedges,
                                                const int* __restrict__ bucketBase,
                                                int* __restrict__ rowptr,
                                                int* __restrict__ srcs, int N, int E) {
    __shared__ int ncnt[256];
    __shared__ int scanb[256];
    int b = blockIdx.x;
    int t = threadIdx.x;
    int eb = bucketBase[b], ee = bucketBase[b + 1];
    ncnt[t] = 0;
    __syncthreads();
    for (int j = eb + t; j < ee; j += 256) {
        unsigned int v = pedges[j];
        atomicAdd(&ncnt[v >> 17], 1);
    }
    __syncthreads();
    int myc = ncnt[t];
    int val = myc;
    scanb[t] = val;
    __syncthreads();
    for (int off = 1; off < 256; off <<= 1) {
        int v2 = (t >= off) ? scanb[t - off] : 0;
        __syncthreads();
        val += v2;
        scanb[t] = val;
        __syncthreads();
    }
    int mybase = val - myc;
    int node = b * 256 + t;
    if (node < N) rowptr[node] = eb + mybase;
    if (b == 0 && t == 0) rowptr[N] = E;
    scanb[t] = mybase;
    ncnt[t] = 0;
    __syncthreads();
    for (int j = eb + t; j < ee; j += 256) {
        unsigned int v = pedges[j];
        int nl = v >> 17;
        int r = atomicAdd(&ncnt[nl], 1);
        srcs[eb + scanb[nl] + r] = (int)(v & 0x1FFFF);
    }
}

// ---------------- weight prep: B^T bf16 + fused classifier ----------------
// A1 layout per node (64 bf16): [x(24) | mean1(24) | 0(16)]
// Bt1[o][k]: k<24 -> W1r[o][k] (self), 24<=k<48 -> W1l[o][k-24] (mean), else 0
// A2 layout per node (128 bf16): [mean2(64) | h(64)]
// Bt2[o][k], o<64: k<64 -> W2l[o][k], else W2r[o][k-64]
// Bt2[64+c][k] = sum_j Wc[c][j] * (k<64 ? W2l[j][k] : W2r[j][k-64])
// bias2[o<64] = b2[o]; bias2[64+c] = bc[c] + sum_j Wc[c][j]*b2[j]
__global__ __launch_bounds__(256) void k_prep(const float* __restrict__ W1l,
                                              const float* __restrict__ W1r,
                                              const float* __restrict__ W2l,
                                              const float* __restrict__ W2r,
                                              const float* __restrict__ Wc,
                                              const float* __restrict__ b2,
                                              const float* __restrict__ bc,
                                              unsigned short* __restrict__ Bt1,
                                              unsigned short* __restrict__ Bt2,
                                              float* __restrict__ bias2) {
    int t = threadIdx.x;
    for (int i = t; i < 64 * 64; i += 256) {
        int o = i >> 6, k = i & 63;
        float v = (k < 24) ? W1r[o * 24 + k] : ((k < 48) ? W1l[o * 24 + k - 24] : 0.f);
        Bt1[i] = f2bf(v);
    }
    for (int i = t; i < 64 * 128; i += 256) {
        int o = i >> 7, k = i & 127;
        float v = (k < 64) ? W2l[o * 64 + k] : W2r[o * 64 + k - 64];
        Bt2[i] = f2bf(v);
    }
    for (int i = t; i < 16 * 128; i += 256) {
        int c = i >> 7, k = i & 127;
        const float* M = (k < 64) ? W2l : W2r;
        int kk = k & 63;
        float s = 0.f;
        for (int j = 0; j < 64; j++) s += Wc[c * 64 + j] * M[j * 64 + kk];
        Bt2[(64 + c) * 128 + k] = f2bf(s);
    }
    for (int i = t; i < 80; i += 256) {
        if (i < 64) bias2[i] = b2[i];
        else {
            int c = i - 64;
            float s = bc[c];
            for (int j = 0; j < 64; j++) s += Wc[c * 64 + j] * b2[j];
            bias2[i] = s;
        }
    }
}

// x fp32 -> A1 bf16 rows (packed pairs); zero mean/pad zones
__global__ __launch_bounds__(256) void k_castx(const float* __restrict__ x,
                                               unsigned int* __restrict__ A1u) {
    int gid = blockIdx.x * 256 + threadIdx.x;
    if (gid >= N_NODES * 32) return;
    int n = gid >> 5, kp = gid & 31;
    unsigned int out = 0;
    if (kp < 12) {
        const float2 v = *(const float2*)(x + n * 24 + kp * 2);
        out = (unsigned int)f2bf(v.x) | ((unsigned int)f2bf(v.y) << 16);
    }
    A1u[gid] = out;
}

// ---------------- aggregations (bf16 gather, fp32 accumulate) ----------------

// 16 lanes per node; lanes 0..11 own a bf16x2 channel pair of x
__global__ __launch_bounds__(256) void k_agg1(const unsigned int* __restrict__ A1u,
                                              const int* __restrict__ rowptr,
                                              const int* __restrict__ srcs,
                                              unsigned int* __restrict__ A1w, int N) {
    int gid = blockIdx.x * 256 + threadIdx.x;
    int node = gid >> 4;
    int lp = gid & 15;
    if (node >= N) return;
    int b = rowptr[node], e = rowptr[node + 1];
    int lpc = (lp < 12) ? lp : 0;
    float ax0 = 0.f, ay0 = 0.f, ax1 = 0.f, ay1 = 0.f;
    float ax2 = 0.f, ay2 = 0.f, ax3 = 0.f, ay3 = 0.f;
    int j = b;
    for (; j + 3 < e; j += 4) {
        int s0 = srcs[j], s1 = srcs[j + 1], s2 = srcs[j + 2], s3 = srcs[j + 3];
        unsigned int u0 = A1u[s0 * 32 + lpc];
        unsigned int u1 = A1u[s1 * 32 + lpc];
        unsigned int u2 = A1u[s2 * 32 + lpc];
        unsigned int u3 = A1u[s3 * 32 + lpc];
        ax0 += bflo(u0); ay0 += bfhi(u0);
        ax1 += bflo(u1); ay1 += bfhi(u1);
        ax2 += bflo(u2); ay2 += bfhi(u2);
        ax3 += bflo(u3); ay3 += bfhi(u3);
    }
    for (; j < e; j++) {
        unsigned int u0 = A1u[srcs[j] * 32 + lpc];
        ax0 += bflo(u0); ay0 += bfhi(u0);
    }
    float inv = 1.f / (float)max(e - b, 1);
    float mx = ((ax0 + ax1) + (ax2 + ax3)) * inv;
    float my = ((ay0 + ay1) + (ay2 + ay3)) * inv;
    if (lp < 12)
        A1w[node * 32 + 12 + lp] = (unsigned int)f2bf(mx) | ((unsigned int)f2bf(my) << 16);
}

// 32 lanes per node; lane owns a bf16x2 pair of h (upper half of A2 row)
__global__ __launch_bounds__(256) void k_agg2(const unsigned int* __restrict__ A2u,
                                              const int* __restrict__ rowptr,
                                              const int* __restrict__ srcs,
                                              unsigned int* __restrict__ A2w, int N) {
    int gid = blockIdx.x * 256 + threadIdx.x;
    int node = gid >> 5;
    int lp = gid & 31;
    if (node >= N) return;
    int b = rowptr[node], e = rowptr[node + 1];
    float ax0 = 0.f, ay0 = 0.f, ax1 = 0.f, ay1 = 0.f;
    float ax2 = 0.f, ay2 = 0.f, ax3 = 0.f, ay3 = 0.f;
    int j = b;
    for (; j + 3 < e; j += 4) {
        int s0 = srcs[j], s1 = srcs[j + 1], s2 = srcs[j + 2], s3 = srcs[j + 3];
        unsigned int u0 = A2u[s0 * 64 + 32 + lp];
        unsigned int u1 = A2u[s1 * 64 + 32 + lp];
        unsigned int u2 = A2u[s2 * 64 + 32 + lp];
        unsigned int u3 = A2u[s3 * 64 + 32 + lp];
        ax0 += bflo(u0); ay0 += bfhi(u0);
        ax1 += bflo(u1); ay1 += bfhi(u1);
        ax2 += bflo(u2); ay2 += bfhi(u2);
        ax3 += bflo(u3); ay3 += bfhi(u3);
    }
    for (; j < e; j++) {
        unsigned int u0 = A2u[srcs[j] * 64 + 32 + lp];
        ax0 += bflo(u0); ay0 += bfhi(u0);
    }
    float inv = 1.f / (float)max(e - b, 1);
    float mx = ((ax0 + ax1) + (ax2 + ax3)) * inv;
    float my = ((ay0 + ay1) + (ay2 + ay3)) * inv;
    A2w[node * 64 + lp] = (unsigned int)f2bf(mx) | ((unsigned int)f2bf(my) << 16);
}

// ---------------- MFMA GEMMs (no LDS; B^T in registers) ----------------

// h = relu(A1 @ Bt1^T + b1), stored bf16 into A2 h-half.  M=N_NODES K=64 N=64
__global__ __launch_bounds__(256) void k_gemm1(const unsigned short* __restrict__ A1,
                                               const unsigned short* __restrict__ Bt1,
                                               const float* __restrict__ b1,
                                               unsigned short* __restrict__ A2s) {
    int wave = (blockIdx.x * 256 + threadIdx.x) >> 6;
    int lane = threadIdx.x & 63;
    int m = lane & 15, quad = lane >> 4;
    if (wave >= NSTRIPS) return;
    short8 bf[4][2];
#pragma unroll
    for (int t = 0; t < 4; t++)
#pragma unroll
        for (int s = 0; s < 2; s++)
            bf[t][s] = *(const short8*)(Bt1 + (t * 16 + m) * 64 + s * 32 + quad * 8);
    float bias[4];
#pragma unroll
    for (int t = 0; t < 4; t++) bias[t] = b1[t * 16 + m];

    int row0 = wave * 16;
    short8 a0 = *(const short8*)(A1 + (row0 + m) * 64 + quad * 8);
    short8 a1 = *(const short8*)(A1 + (row0 + m) * 64 + 32 + quad * 8);
    float4_ acc[4];
#pragma unroll
    for (int t = 0; t < 4; t++) {
        float4_ c = {0.f, 0.f, 0.f, 0.f};
        c = __builtin_amdgcn_mfma_f32_16x16x32_bf16(a0, bf[t][0], c, 0, 0, 0);
        c = __builtin_amdgcn_mfma_f32_16x16x32_bf16(a1, bf[t][1], c, 0, 0, 0);
        acc[t] = c;
    }
#pragma unroll
    for (int t = 0; t < 4; t++) {
        int col = t * 16 + m;
#pragma unroll
        for (int r = 0; r < 4; r++) {
            int row = row0 + quad * 4 + r;
            float v = fmaxf(acc[t][r] + bias[t], 0.f);
            A2s[row * 128 + 64 + col] = f2bf(v);
        }
    }
}

// [emb|logits] = A2 @ Bt2^T + bias2.  M=N_NODES K=128 N=80.
// emb written fp32 IN PLACE over A2 rows (same byte ranges) — per-wave
// loads complete (data dep) before stores.
__global__ __launch_bounds__(256) void k_gemm2(const unsigned short* __restrict__ Bt2,
                                               const float* __restrict__ bias2,
                                               unsigned short* A2s,
                                               float* logits) {
    int wave = (blockIdx.x * 256 + threadIdx.x) >> 6;
    int lane = threadIdx.x & 63;
    int m = lane & 15, quad = lane >> 4;
    if (wave >= NSTRIPS) return;
    short8 bf[5][4];
#pragma unroll
    for (int t = 0; t < 5; t++)
#pragma unroll
        for (int s = 0; s < 4; s++)
            bf[t][s] = *(const short8*)(Bt2 + (t * 16 + m) * 128 + s * 32 + quad * 8);
    float bias[5];
#pragma unroll
    for (int t = 0; t < 5; t++) bias[t] = bias2[t * 16 + m];

    int row0 = wave * 16;
    short8 a[4];
#pragma unroll
    for (int s = 0; s < 4; s++)
        a[s] = *(const short8*)(A2s + (row0 + m) * 128 + s * 32 + quad * 8);
    float4_ acc[5];
#pragma unroll
    for (int t = 0; t < 5; t++) {
        float4_ c = {0.f, 0.f, 0.f, 0.f};
#pragma unroll
        for (int s = 0; s < 4; s++)
            c = __builtin_amdgcn_mfma_f32_16x16x32_bf16(a[s], bf[t][s], c, 0, 0, 0);
        acc[t] = c;
    }
    float* embp = (float*)A2s;  // emb row n occupies the same 256B as A2 row n
#pragma unroll
    for (int t = 0; t < 4; t++) {
#pragma unroll
        for (int r = 0; r < 4; r++) {
            int row = row0 + quad * 4 + r;
            embp[row * 64 + t * 16 + m] = acc[t][r] + bias[t];
        }
    }
#pragma unroll
    for (int r = 0; r < 4; r++) {
        int row = row0 + quad * 4 + r;
        logits[row * 16 + m] = acc[4][r] + bias[4];
    }
}

// ---------------- launch ----------------

extern "C" void kernel_launch(void* const* d_in, const int* in_sizes, int n_in,
                              void* d_out, int out_size, void* d_ws, size_t ws_size,
                              hipStream_t stream) {
    const float* x = (const float*)d_in[0];
    const int* edge = (const int*)d_in[1];
    const int* srcIdx = edge;
    const int* dstIdx = edge + N_EDGES;
    const float* W1l = (const float*)d_in[2];
    const float* b1  = (const float*)d_in[3];
    const float* W1r = (const float*)d_in[4];
    const float* W2l = (const float*)d_in[5];
    const float* b2  = (const float*)d_in[6];
    const float* W2r = (const float*)d_in[7];
    const float* Wc  = (const float*)d_in[8];
    const float* bc  = (const float*)d_in[9];

    float* logits = (float*)d_out;
    // A2 (bf16 [mean2|h], 256B rows) aliases the emb output region byte-for-byte
    unsigned short* A2s = (unsigned short*)((float*)d_out + (size_t)N_NODES * N_CLASSES);
    unsigned int* A2u = (unsigned int*)A2s;

    char* w = (char*)d_ws;
    auto carve = [&](size_t bytes) {
        char* p = w;
        w += (bytes + 255) & ~(size_t)255;
        return p;
    };
    int* rowptr          = (int*)carve((N_NODES + 1) * sizeof(int));
    int* srcs            = (int*)carve((size_t)N_EDGES * sizeof(int));
    unsigned int* A1u    = (unsigned int*)carve((size_t)N_NODES * 32 * sizeof(unsigned int));
    int* bucketCnt       = (int*)carve(NBUCK * sizeof(int));
    int* bucketBase      = (int*)carve((NBUCK + 1) * sizeof(int));
    int* bucketFill      = (int*)carve(NBUCK * sizeof(int));
    unsigned short* Bt1  = (unsigned short*)carve(64 * 64 * sizeof(unsigned short));
    unsigned short* Bt2  = (unsigned short*)carve(80 * 128 * sizeof(unsigned short));
    float* bias2         = (float*)carve(80 * sizeof(float));

    // pedges aliases A1 (A1 is written by k_castx AFTER k_bucket consumes pedges)
    unsigned int* pedges = A1u;
    unsigned short* A1s = (unsigned short*)A1u;

    k_prep<<<1, 256, 0, stream>>>(W1l, W1r, W2l, W2r, Wc, b2, bc, Bt1, Bt2, bias2);

    hipMemsetAsync(bucketCnt, 0, NBUCK * sizeof(int), stream);
    k_phist<<<256, 256, 0, stream>>>(dstIdx, bucketCnt, N_EDGES);
    k_scanb<<<1, 512, 0, stream>>>(bucketCnt, bucketBase, bucketFill, N_EDGES);
    int pbl = (N_EDGES + CHUNK - 1) / CHUNK;
    k_part<<<pbl, 256, 0, stream>>>(srcIdx, dstIdx, bucketFill, pedges, N_EDGES);
    k_bucket<<<NBUCK, 256, 0, stream>>>(pedges, bucketBase, rowptr, srcs,
                                        N_NODES, N_EDGES);

    k_castx<<<(N_NODES * 32 + 255) / 256, 256, 0, stream>>>(x, A1u);
    k_agg1<<<(N_NODES * 16 + 255) / 256, 256, 0, stream>>>(A1u, rowptr, srcs, A1u, N_NODES);
    k_gemm1<<<(NSTRIPS + 3) / 4, 256, 0, stream>>>(A1s, Bt1, b1, A2s);
    k_agg2<<<(N_NODES * 32 + 255) / 256, 256, 0, stream>>>(A2u, rowptr, srcs, A2u, N_NODES);
    k_gemm2<<<(NSTRIPS + 3) / 4, 256, 0, stream>>>(Bt2, bias2, A2s, logits);
}

// Round 4
// 368.981 us; speedup vs baseline: 2.7943x; 1.0383x over previous
//
#include <hip/hip_runtime.h>

#define N_NODES 100000
#define N_EDGES 3200000
#define IN_CH 24
#define HIDDEN 64
#define N_CLASSES 16

#define NBUCK 391      // ceil(N_NODES / 256)
#define CHUNK 8192     // edges per partition block
#define NSTRIPS (N_NODES / 16)   // 6250 exact

typedef __attribute__((ext_vector_type(8))) short short8;
typedef __attribute__((ext_vector_type(4))) float float4_;

__device__ __forceinline__ unsigned short f2bf(float f) {
    union { float f; unsigned int u; } v; v.f = f;
    unsigned int u = v.u;
    return (unsigned short)((u + 0x7FFFu + ((u >> 16) & 1u)) >> 16);
}
__device__ __forceinline__ float bflo(unsigned int u) {
    union { unsigned int u; float f; } v; v.u = u << 16; return v.f;
}
__device__ __forceinline__ float bfhi(unsigned int u) {
    union { unsigned int u; float f; } v; v.u = u & 0xFFFF0000u; return v.f;
}

// ---------------- CSR build (two-level partition, from R1) ----------------

__global__ __launch_bounds__(256) void k_phist(const int* __restrict__ dst,
                                               int* __restrict__ bucketCnt, int E) {
    __shared__ int hist[NBUCK];
    int t = threadIdx.x;
    for (int i = t; i < NBUCK; i += 256) hist[i] = 0;
    __syncthreads();
    for (int e = blockIdx.x * 256 + t; e < E; e += 256 * gridDim.x)
        atomicAdd(&hist[dst[e] >> 8], 1);
    __syncthreads();
    for (int i = t; i < NBUCK; i += 256)
        if (hist[i]) atomicAdd(&bucketCnt[i], hist[i]);
}

__global__ __launch_bounds__(512) void k_scanb(const int* __restrict__ bucketCnt,
                                               int* __restrict__ bucketBase,
                                               int* __restrict__ bucketFill, int E) {
    __shared__ int lds[512];
    int t = threadIdx.x;
    int c = (t < NBUCK) ? bucketCnt[t] : 0;
    int val = c;
    lds[t] = val;
    __syncthreads();
    for (int off = 1; off < 512; off <<= 1) {
        int v = (t >= off) ? lds[t - off] : 0;
        __syncthreads();
        val += v;
        lds[t] = val;
        __syncthreads();
    }
    if (t < NBUCK) {
        int ex = val - c;
        bucketBase[t] = ex;
        bucketFill[t] = ex;
    }
    if (t == 0) bucketBase[NBUCK] = E;
}

__global__ __launch_bounds__(256) void k_part(const int* __restrict__ src,
                                              const int* __restrict__ dst,
                                              int* __restrict__ bucketFill,
                                              unsigned int* __restrict__ pedges, int E) {
    __shared__ int cntL[NBUCK];
    __shared__ int baseL[NBUCK];
    int t = threadIdx.x;
    int cbeg = blockIdx.x * CHUNK;
    int cend = min(cbeg + CHUNK, E);
    for (int i = t; i < NBUCK; i += 256) cntL[i] = 0;
    __syncthreads();
    for (int j = cbeg + t; j < cend; j += 256)
        atomicAdd(&cntL[dst[j] >> 8], 1);
    __syncthreads();
    for (int i = t; i < NBUCK; i += 256) {
        int c = cntL[i];
        if (c) baseL[i] = atomicAdd(&bucketFill[i], c);
        cntL[i] = 0;
    }
    __syncthreads();
    for (int j = cbeg + t; j < cend; j += 256) {
        int d = dst[j], s = src[j];
        int bk = d >> 8;
        int r = atomicAdd(&cntL[bk], 1);
        pedges[baseL[bk] + r] = ((unsigned int)(d & 255) << 17) | (unsigned int)s;
    }
}

__global__ __launch_bounds__(256) void k_bucket(const unsigned int* __restrict__ pedges,
                                                const int* __restrict__ bucketBase,
                                                int* __restrict__ rowptr,
                                                int* __restrict__ srcs, int N, int E) {
    __shared__ int ncnt[256];
    __shared__ int scanb[256];
    int b = blockIdx.x;
    int t = threadIdx.x;
    int eb = bucketBase[b], ee = bucketBase[b + 1];
    ncnt[t] = 0;
    __syncthreads();
    for (int j = eb + t; j < ee; j += 256) {
        unsigned int v = pedges[j];
        atomicAdd(&ncnt[v >> 17], 1);
    }
    __syncthreads();
    int myc = ncnt[t];
    int val = myc;
    scanb[t] = val;
    __syncthreads();
    for (int off = 1; off < 256; off <<= 1) {
        int v2 = (t >= off) ? scanb[t - off] : 0;
        __syncthreads();
        val += v2;
        scanb[t] = val;
        __syncthreads();
    }
    int mybase = val - myc;
    int node = b * 256 + t;
    if (node < N) rowptr[node] = eb + mybase;
    if (b == 0 && t == 0) rowptr[N] = E;
    scanb[t] = mybase;
    ncnt[t] = 0;
    __syncthreads();
    for (int j = eb + t; j < ee; j += 256) {
        unsigned int v = pedges[j];
        int nl = v >> 17;
        int r = atomicAdd(&ncnt[nl], 1);
        srcs[eb + scanb[nl] + r] = (int)(v & 0x1FFFF);
    }
}

// ---------------- weight prep ----------------

__global__ __launch_bounds__(256) void k_prep(const float* __restrict__ W1l,
                                              const float* __restrict__ W1r,
                                              const float* __restrict__ W2l,
                                              const float* __restrict__ W2r,
                                              const float* __restrict__ Wc,
                                              const float* __restrict__ b2,
                                              const float* __restrict__ bc,
                                              unsigned short* __restrict__ Bt1,
                                              unsigned short* __restrict__ Bt2,
                                              float* __restrict__ bias2) {
    int t = threadIdx.x;
    for (int i = t; i < 64 * 64; i += 256) {
        int o = i >> 6, k = i & 63;
        float v = (k < 24) ? W1r[o * 24 + k] : ((k < 48) ? W1l[o * 24 + k - 24] : 0.f);
        Bt1[i] = f2bf(v);
    }
    for (int i = t; i < 64 * 128; i += 256) {
        int o = i >> 7, k = i & 127;
        float v = (k < 64) ? W2l[o * 64 + k] : W2r[o * 64 + k - 64];
        Bt2[i] = f2bf(v);
    }
    for (int i = t; i < 16 * 128; i += 256) {
        int c = i >> 7, k = i & 127;
        const float* M = (k < 64) ? W2l : W2r;
        int kk = k & 63;
        float s = 0.f;
        for (int j = 0; j < 64; j++) s += Wc[c * 64 + j] * M[j * 64 + kk];
        Bt2[(64 + c) * 128 + k] = f2bf(s);
    }
    for (int i = t; i < 80; i += 256) {
        if (i < 64) bias2[i] = b2[i];
        else {
            int c = i - 64;
            float s = bc[c];
            for (int j = 0; j < 64; j++) s += Wc[c * 64 + j] * b2[j];
            bias2[i] = s;
        }
    }
}

__global__ __launch_bounds__(256) void k_castx(const float* __restrict__ x,
                                               unsigned int* __restrict__ A1u) {
    int gid = blockIdx.x * 256 + threadIdx.x;
    if (gid >= N_NODES * 32) return;
    int n = gid >> 5, kp = gid & 31;
    unsigned int out = 0;
    if (kp < 12) {
        const float2 v = *(const float2*)(x + n * 24 + kp * 2);
        out = (unsigned int)f2bf(v.x) | ((unsigned int)f2bf(v.y) << 16);
    }
    A1u[gid] = out;
}

// ---------------- aggregations: one wave per node, dwordx4 gathers ----------

// agg1: 4 lanes/edge (3 load 16B = 48B x-row), 16 edges/group-iter, unroll 2
__global__ __launch_bounds__(256) void k_agg1(const unsigned int* __restrict__ A1u,
                                              const int* __restrict__ rowptr,
                                              const int* __restrict__ srcs,
                                              unsigned int* __restrict__ A1w, int N) {
    int node = (blockIdx.x * 256 + threadIdx.x) >> 6;
    int lane = threadIdx.x & 63;
    if (node >= N) return;
    int b = rowptr[node], e = rowptr[node + 1];
    int grp = lane >> 2;    // 0..15 edge slot
    int sub = lane & 3;     // 16B chunk within 48B payload (sub<3 active)
    float a0 = 0.f, a1 = 0.f, a2 = 0.f, a3 = 0.f;
    float a4 = 0.f, a5 = 0.f, a6 = 0.f, a7 = 0.f;
    int subc = (sub < 3) ? sub : 0;
    for (int j = b; j < e; j += 32) {
        int j0 = j + grp, j1 = j + 16 + grp;
        int s0 = srcs[min(j0, e - 1)];
        int s1 = srcs[min(j1, e - 1)];
        uint4 u0 = *(const uint4*)(A1u + (size_t)s0 * 32 + subc * 4);
        uint4 u1 = *(const uint4*)(A1u + (size_t)s1 * 32 + subc * 4);
        if (j0 < e) {
            a0 += bflo(u0.x); a1 += bfhi(u0.x);
            a2 += bflo(u0.y); a3 += bfhi(u0.y);
            a4 += bflo(u0.z); a5 += bfhi(u0.z);
            a6 += bflo(u0.w); a7 += bfhi(u0.w);
        }
        if (j1 < e) {
            a0 += bflo(u1.x); a1 += bfhi(u1.x);
            a2 += bflo(u1.y); a3 += bfhi(u1.y);
            a4 += bflo(u1.z); a5 += bfhi(u1.z);
            a6 += bflo(u1.w); a7 += bfhi(u1.w);
        }
    }
#pragma unroll
    for (int m = 4; m <= 32; m <<= 1) {
        a0 += __shfl_xor(a0, m, 64); a1 += __shfl_xor(a1, m, 64);
        a2 += __shfl_xor(a2, m, 64); a3 += __shfl_xor(a3, m, 64);
        a4 += __shfl_xor(a4, m, 64); a5 += __shfl_xor(a5, m, 64);
        a6 += __shfl_xor(a6, m, 64); a7 += __shfl_xor(a7, m, 64);
    }
    if (lane < 3) {
        float inv = 1.f / (float)max(e - b, 1);
        uint4 o;
        o.x = (unsigned int)f2bf(a0 * inv) | ((unsigned int)f2bf(a1 * inv) << 16);
        o.y = (unsigned int)f2bf(a2 * inv) | ((unsigned int)f2bf(a3 * inv) << 16);
        o.z = (unsigned int)f2bf(a4 * inv) | ((unsigned int)f2bf(a5 * inv) << 16);
        o.w = (unsigned int)f2bf(a6 * inv) | ((unsigned int)f2bf(a7 * inv) << 16);
        *(uint4*)(A1w + (size_t)node * 32 + 12 + lane * 4) = o;
    }
}

// agg2: 8 lanes/edge (16B each = 128B h-row), 8 edges/group-iter, unroll 2
__global__ __launch_bounds__(256) void k_agg2(const unsigned int* __restrict__ A2u,
                                              const int* __restrict__ rowptr,
                                              const int* __restrict__ srcs,
                                              unsigned int* __restrict__ A2w, int N) {
    int node = (blockIdx.x * 256 + threadIdx.x) >> 6;
    int lane = threadIdx.x & 63;
    if (node >= N) return;
    int b = rowptr[node], e = rowptr[node + 1];
    int grp = lane >> 3;    // 0..7 edge slot
    int sub = lane & 7;     // 16B chunk within 128B h payload
    float a0 = 0.f, a1 = 0.f, a2 = 0.f, a3 = 0.f;
    float a4 = 0.f, a5 = 0.f, a6 = 0.f, a7 = 0.f;
    for (int j = b; j < e; j += 16) {
        int j0 = j + grp, j1 = j + 8 + grp;
        int s0 = srcs[min(j0, e - 1)];
        int s1 = srcs[min(j1, e - 1)];
        uint4 u0 = *(const uint4*)(A2u + (size_t)s0 * 64 + 32 + sub * 4);
        uint4 u1 = *(const uint4*)(A2u + (size_t)s1 * 64 + 32 + sub * 4);
        if (j0 < e) {
            a0 += bflo(u0.x); a1 += bfhi(u0.x);
            a2 += bflo(u0.y); a3 += bfhi(u0.y);
            a4 += bflo(u0.z); a5 += bfhi(u0.z);
            a6 += bflo(u0.w); a7 += bfhi(u0.w);
        }
        if (j1 < e) {
            a0 += bflo(u1.x); a1 += bfhi(u1.x);
            a2 += bflo(u1.y); a3 += bfhi(u1.y);
            a4 += bflo(u1.z); a5 += bfhi(u1.z);
            a6 += bflo(u1.w); a7 += bfhi(u1.w);
        }
    }
#pragma unroll
    for (int m = 8; m <= 32; m <<= 1) {
        a0 += __shfl_xor(a0, m, 64); a1 += __shfl_xor(a1, m, 64);
        a2 += __shfl_xor(a2, m, 64); a3 += __shfl_xor(a3, m, 64);
        a4 += __shfl_xor(a4, m, 64); a5 += __shfl_xor(a5, m, 64);
        a6 += __shfl_xor(a6, m, 64); a7 += __shfl_xor(a7, m, 64);
    }
    if (lane < 8) {
        float inv = 1.f / (float)max(e - b, 1);
        uint4 o;
        o.x = (unsigned int)f2bf(a0 * inv) | ((unsigned int)f2bf(a1 * inv) << 16);
        o.y = (unsigned int)f2bf(a2 * inv) | ((unsigned int)f2bf(a3 * inv) << 16);
        o.z = (unsigned int)f2bf(a4 * inv) | ((unsigned int)f2bf(a5 * inv) << 16);
        o.w = (unsigned int)f2bf(a6 * inv) | ((unsigned int)f2bf(a7 * inv) << 16);
        *(uint4*)(A2w + (size_t)node * 64 + lane * 4) = o;
    }
}

// ---------------- MFMA GEMMs (no LDS; B^T in registers) ----------------

__global__ __launch_bounds__(256) void k_gemm1(const unsigned short* __restrict__ A1,
                                               const unsigned short* __restrict__ Bt1,
                                               const float* __restrict__ b1,
                                               unsigned short* __restrict__ A2s) {
    int wave = (blockIdx.x * 256 + threadIdx.x) >> 6;
    int lane = threadIdx.x & 63;
    int m = lane & 15, quad = lane >> 4;
    if (wave >= NSTRIPS) return;
    short8 bf[4][2];
#pragma unroll
    for (int t = 0; t < 4; t++)
#pragma unroll
        for (int s = 0; s < 2; s++)
            bf[t][s] = *(const short8*)(Bt1 + (t * 16 + m) * 64 + s * 32 + quad * 8);
    float bias[4];
#pragma unroll
    for (int t = 0; t < 4; t++) bias[t] = b1[t * 16 + m];

    int row0 = wave * 16;
    short8 a0 = *(const short8*)(A1 + (row0 + m) * 64 + quad * 8);
    short8 a1 = *(const short8*)(A1 + (row0 + m) * 64 + 32 + quad * 8);
    float4_ acc[4];
#pragma unroll
    for (int t = 0; t < 4; t++) {
        float4_ c = {0.f, 0.f, 0.f, 0.f};
        c = __builtin_amdgcn_mfma_f32_16x16x32_bf16(a0, bf[t][0], c, 0, 0, 0);
        c = __builtin_amdgcn_mfma_f32_16x16x32_bf16(a1, bf[t][1], c, 0, 0, 0);
        acc[t] = c;
    }
#pragma unroll
    for (int t = 0; t < 4; t++) {
        int col = t * 16 + m;
#pragma unroll
        for (int r = 0; r < 4; r++) {
            int row = row0 + quad * 4 + r;
            float v = fmaxf(acc[t][r] + bias[t], 0.f);
            A2s[row * 128 + 64 + col] = f2bf(v);
        }
    }
}

__global__ __launch_bounds__(256) void k_gemm2(const unsigned short* __restrict__ Bt2,
                                               const float* __restrict__ bias2,
                                               unsigned short* A2s,
                                               float* logits) {
    int wave = (blockIdx.x * 256 + threadIdx.x) >> 6;
    int lane = threadIdx.x & 63;
    int m = lane & 15, quad = lane >> 4;
    if (wave >= NSTRIPS) return;
    short8 bf[5][4];
#pragma unroll
    for (int t = 0; t < 5; t++)
#pragma unroll
        for (int s = 0; s < 4; s++)
            bf[t][s] = *(const short8*)(Bt2 + (t * 16 + m) * 128 + s * 32 + quad * 8);
    float bias[5];
#pragma unroll
    for (int t = 0; t < 5; t++) bias[t] = bias2[t * 16 + m];

    int row0 = wave * 16;
    short8 a[4];
#pragma unroll
    for (int s = 0; s < 4; s++)
        a[s] = *(const short8*)(A2s + (row0 + m) * 128 + s * 32 + quad * 8);
    float4_ acc[5];
#pragma unroll
    for (int t = 0; t < 5; t++) {
        float4_ c = {0.f, 0.f, 0.f, 0.f};
#pragma unroll
        for (int s = 0; s < 4; s++)
            c = __builtin_amdgcn_mfma_f32_16x16x32_bf16(a[s], bf[t][s], c, 0, 0, 0);
        acc[t] = c;
    }
    float* embp = (float*)A2s;
#pragma unroll
    for (int t = 0; t < 4; t++) {
#pragma unroll
        for (int r = 0; r < 4; r++) {
            int row = row0 + quad * 4 + r;
            embp[row * 64 + t * 16 + m] = acc[t][r] + bias[t];
        }
    }
#pragma unroll
    for (int r = 0; r < 4; r++) {
        int row = row0 + quad * 4 + r;
        logits[row * 16 + m] = acc[4][r] + bias[4];
    }
}

// ---------------- launch ----------------

extern "C" void kernel_launch(void* const* d_in, const int* in_sizes, int n_in,
                              void* d_out, int out_size, void* d_ws, size_t ws_size,
                              hipStream_t stream) {
    const float* x = (const float*)d_in[0];
    const int* edge = (const int*)d_in[1];
    const int* srcIdx = edge;
    const int* dstIdx = edge + N_EDGES;
    const float* W1l = (const float*)d_in[2];
    const float* b1  = (const float*)d_in[3];
    const float* W1r = (const float*)d_in[4];
    const float* W2l = (const float*)d_in[5];
    const float* b2  = (const float*)d_in[6];
    const float* W2r = (const float*)d_in[7];
    const float* Wc  = (const float*)d_in[8];
    const float* bc  = (const float*)d_in[9];

    float* logits = (float*)d_out;
    unsigned short* A2s = (unsigned short*)((float*)d_out + (size_t)N_NODES * N_CLASSES);
    unsigned int* A2u = (unsigned int*)A2s;

    char* w = (char*)d_ws;
    auto carve = [&](size_t bytes) {
        char* p = w;
        w += (bytes + 255) & ~(size_t)255;
        return p;
    };
    int* rowptr          = (int*)carve((N_NODES + 1) * sizeof(int));
    int* srcs            = (int*)carve((size_t)N_EDGES * sizeof(int));
    unsigned int* A1u    = (unsigned int*)carve((size_t)N_NODES * 32 * sizeof(unsigned int));
    int* bucketCnt       = (int*)carve(NBUCK * sizeof(int));
    int* bucketBase      = (int*)carve((NBUCK + 1) * sizeof(int));
    int* bucketFill      = (int*)carve(NBUCK * sizeof(int));
    unsigned short* Bt1  = (unsigned short*)carve(64 * 64 * sizeof(unsigned short));
    unsigned short* Bt2  = (unsigned short*)carve(80 * 128 * sizeof(unsigned short));
    float* bias2         = (float*)carve(80 * sizeof(float));

    unsigned int* pedges = A1u;
    unsigned short* A1s = (unsigned short*)A1u;

    k_prep<<<1, 256, 0, stream>>>(W1l, W1r, W2l, W2r, Wc, b2, bc, Bt1, Bt2, bias2);

    hipMemsetAsync(bucketCnt, 0, NBUCK * sizeof(int), stream);
    k_phist<<<256, 256, 0, stream>>>(dstIdx, bucketCnt, N_EDGES);
    k_scanb<<<1, 512, 0, stream>>>(bucketCnt, bucketBase, bucketFill, N_EDGES);
    int pbl = (N_EDGES + CHUNK - 1) / CHUNK;
    k_part<<<pbl, 256, 0, stream>>>(srcIdx, dstIdx, bucketFill, pedges, N_EDGES);
    k_bucket<<<NBUCK, 256, 0, stream>>>(pedges, bucketBase, rowptr, srcs,
                                        N_NODES, N_EDGES);

    k_castx<<<(N_NODES * 32 + 255) / 256, 256, 0, stream>>>(x, A1u);
    k_agg1<<<(N_NODES * 64 + 255) / 256, 256, 0, stream>>>(A1u, rowptr, srcs, A1u, N_NODES);
    k_gemm1<<<(NSTRIPS + 3) / 4, 256, 0, stream>>>(A1s, Bt1, b1, A2s);
    k_agg2<<<(N_NODES * 64 + 255) / 256, 256, 0, stream>>>(A2u, rowptr, srcs, A2u, N_NODES);
    k_gemm2<<<(NSTRIPS + 3) / 4, 256, 0, stream>>>(Bt2, bias2, A2s, logits);
}

// Round 5
// 354.062 us; speedup vs baseline: 2.9121x; 1.0421x over previous
//
#include <hip/hip_runtime.h>

#define N_NODES 100000
#define N_EDGES 3200000
#define IN_CH 24
#define HIDDEN 64
#define N_CLASSES 16

#define NBUCK 391      // ceil(N_NODES / 256)
#define CHUNK 8192     // edges per partition block
#define NSTRIPS (N_NODES / 16)   // 6250 exact

typedef __attribute__((ext_vector_type(8))) short short8;
typedef __attribute__((ext_vector_type(4))) float float4_;

__device__ __forceinline__ unsigned short f2bf(float f) {
    union { float f; unsigned int u; } v; v.f = f;
    unsigned int u = v.u;
    return (unsigned short)((u + 0x7FFFu + ((u >> 16) & 1u)) >> 16);
}
__device__ __forceinline__ float bflo(unsigned int u) {
    union { unsigned int u; float f; } v; v.u = u << 16; return v.f;
}
__device__ __forceinline__ float bfhi(unsigned int u) {
    union { unsigned int u; float f; } v; v.u = u & 0xFFFF0000u; return v.f;
}

// ---------------- CSR build (two-level partition) ----------------

__global__ __launch_bounds__(256) void k_phist(const int* __restrict__ dst,
                                               int* __restrict__ bucketCnt, int E) {
    __shared__ int hist[NBUCK];
    int t = threadIdx.x;
    for (int i = t; i < NBUCK; i += 256) hist[i] = 0;
    __syncthreads();
    for (int e = blockIdx.x * 256 + t; e < E; e += 256 * gridDim.x)
        atomicAdd(&hist[dst[e] >> 8], 1);
    __syncthreads();
    for (int i = t; i < NBUCK; i += 256)
        if (hist[i]) atomicAdd(&bucketCnt[i], hist[i]);
}

__global__ __launch_bounds__(512) void k_scanb(const int* __restrict__ bucketCnt,
                                               int* __restrict__ bucketBase,
                                               int* __restrict__ bucketFill,
                                               int* __restrict__ srcs, int E) {
    __shared__ int lds[512];
    int t = threadIdx.x;
    int c = (t < NBUCK) ? bucketCnt[t] : 0;
    int val = c;
    lds[t] = val;
    __syncthreads();
    for (int off = 1; off < 512; off <<= 1) {
        int v = (t >= off) ? lds[t - off] : 0;
        __syncthreads();
        val += v;
        lds[t] = val;
        __syncthreads();
    }
    if (t < NBUCK) {
        int ex = val - c;
        bucketBase[t] = ex;
        bucketFill[t] = ex;
    }
    if (t == 0) bucketBase[NBUCK] = E;
    // zero-fill srcs slack tail so OOB-masked gathers read node 0 (valid mem)
    if (t < 32) srcs[E + t] = 0;
}

__global__ __launch_bounds__(256) void k_part(const int* __restrict__ src,
                                              const int* __restrict__ dst,
                                              int* __restrict__ bucketFill,
                                              unsigned int* __restrict__ pedges, int E) {
    __shared__ int cntL[NBUCK];
    __shared__ int baseL[NBUCK];
    int t = threadIdx.x;
    int cbeg = blockIdx.x * CHUNK;
    int cend = min(cbeg + CHUNK, E);
    for (int i = t; i < NBUCK; i += 256) cntL[i] = 0;
    __syncthreads();
    for (int j = cbeg + t; j < cend; j += 256)
        atomicAdd(&cntL[dst[j] >> 8], 1);
    __syncthreads();
    for (int i = t; i < NBUCK; i += 256) {
        int c = cntL[i];
        if (c) baseL[i] = atomicAdd(&bucketFill[i], c);
        cntL[i] = 0;
    }
    __syncthreads();
    for (int j = cbeg + t; j < cend; j += 256) {
        int d = dst[j], s = src[j];
        int bk = d >> 8;
        int r = atomicAdd(&cntL[bk], 1);
        pedges[baseL[bk] + r] = ((unsigned int)(d & 255) << 17) | (unsigned int)s;
    }
}

__global__ __launch_bounds__(256) void k_bucket(const unsigned int* __restrict__ pedges,
                                                const int* __restrict__ bucketBase,
                                                int* __restrict__ rowptr,
                                                int* __restrict__ srcs, int N, int E) {
    __shared__ int ncnt[256];
    __shared__ int scanb[256];
    int b = blockIdx.x;
    int t = threadIdx.x;
    int eb = bucketBase[b], ee = bucketBase[b + 1];
    ncnt[t] = 0;
    __syncthreads();
    for (int j = eb + t; j < ee; j += 256) {
        unsigned int v = pedges[j];
        atomicAdd(&ncnt[v >> 17], 1);
    }
    __syncthreads();
    int myc = ncnt[t];
    int val = myc;
    scanb[t] = val;
    __syncthreads();
    for (int off = 1; off < 256; off <<= 1) {
        int v2 = (t >= off) ? scanb[t - off] : 0;
        __syncthreads();
        val += v2;
        scanb[t] = val;
        __syncthreads();
    }
    int mybase = val - myc;
    int node = b * 256 + t;
    if (node < N) rowptr[node] = eb + mybase;
    if (b == 0 && t == 0) rowptr[N] = E;
    scanb[t] = mybase;
    ncnt[t] = 0;
    __syncthreads();
    for (int j = eb + t; j < ee; j += 256) {
        unsigned int v = pedges[j];
        int nl = v >> 17;
        int r = atomicAdd(&ncnt[nl], 1);
        srcs[eb + scanb[nl] + r] = (int)(v & 0x1FFFF);
    }
}

// ---------------- weight prep ----------------

__global__ __launch_bounds__(256) void k_prep(const float* __restrict__ W1l,
                                              const float* __restrict__ W1r,
                                              const float* __restrict__ W2l,
                                              const float* __restrict__ W2r,
                                              const float* __restrict__ Wc,
                                              const float* __restrict__ b2,
                                              const float* __restrict__ bc,
                                              unsigned short* __restrict__ Bt1,
                                              unsigned short* __restrict__ Bt2,
                                              float* __restrict__ bias2) {
    int t = threadIdx.x;
    for (int i = t; i < 64 * 64; i += 256) {
        int o = i >> 6, k = i & 63;
        float v = (k < 24) ? W1r[o * 24 + k] : ((k < 48) ? W1l[o * 24 + k - 24] : 0.f);
        Bt1[i] = f2bf(v);
    }
    for (int i = t; i < 64 * 128; i += 256) {
        int o = i >> 7, k = i & 127;
        float v = (k < 64) ? W2l[o * 64 + k] : W2r[o * 64 + k - 64];
        Bt2[i] = f2bf(v);
    }
    for (int i = t; i < 16 * 128; i += 256) {
        int c = i >> 7, k = i & 127;
        const float* M = (k < 64) ? W2l : W2r;
        int kk = k & 63;
        float s = 0.f;
        for (int j = 0; j < 64; j++) s += Wc[c * 64 + j] * M[j * 64 + kk];
        Bt2[(64 + c) * 128 + k] = f2bf(s);
    }
    for (int i = t; i < 80; i += 256) {
        if (i < 64) bias2[i] = b2[i];
        else {
            int c = i - 64;
            float s = bc[c];
            for (int j = 0; j < 64; j++) s += Wc[c * 64 + j] * b2[j];
            bias2[i] = s;
        }
    }
}

// x fp32 -> A1 rows (128B: x|mean|pad) AND compact xc rows (64B: x|pad)
__global__ __launch_bounds__(256) void k_castx(const float* __restrict__ x,
                                               unsigned int* __restrict__ A1u,
                                               unsigned int* __restrict__ XCu) {
    int gid = blockIdx.x * 256 + threadIdx.x;
    if (gid >= N_NODES * 32) return;
    int n = gid >> 5, kp = gid & 31;
    unsigned int out = 0;
    if (kp < 12) {
        const float2 v = *(const float2*)(x + n * 24 + kp * 2);
        out = (unsigned int)f2bf(v.x) | ((unsigned int)f2bf(v.y) << 16);
    }
    A1u[gid] = out;
    if (kp < 16) XCu[n * 16 + kp] = out;
}

// ---------------- aggregations: masked uint4 gathers, deep pipeline --------

// agg1: gather 64B xc rows, 4 lanes/edge, 16 slots x 2 loads = 32 edges/iter
__global__ __launch_bounds__(256) void k_agg1(const unsigned int* __restrict__ XCu,
                                              const int* __restrict__ rowptr,
                                              const int* __restrict__ srcs,
                                              unsigned int* __restrict__ A1w, int N) {
    int node = (blockIdx.x * 256 + threadIdx.x) >> 6;
    int lane = threadIdx.x & 63;
    if (node >= N) return;
    int b = rowptr[node], e = rowptr[node + 1];
    int grp = lane >> 2;    // 0..15 edge slot
    int sub = lane & 3;     // 16B chunk of 64B row
    float a0 = 0.f, a1 = 0.f, a2 = 0.f, a3 = 0.f;
    float a4 = 0.f, a5 = 0.f, a6 = 0.f, a7 = 0.f;
    for (int j = b; j < e; j += 32) {
        int j0 = j + grp, j1 = j0 + 16;
        int s0 = srcs[j0];
        int s1 = srcs[j1];
        uint4 u0 = *(const uint4*)(XCu + (size_t)s0 * 16 + sub * 4);
        uint4 u1 = *(const uint4*)(XCu + (size_t)s1 * 16 + sub * 4);
        if (j0 >= e) { u0.x = 0; u0.y = 0; u0.z = 0; u0.w = 0; }
        if (j1 >= e) { u1.x = 0; u1.y = 0; u1.z = 0; u1.w = 0; }
        a0 += bflo(u0.x); a1 += bfhi(u0.x);
        a2 += bflo(u0.y); a3 += bfhi(u0.y);
        a4 += bflo(u0.z); a5 += bfhi(u0.z);
        a6 += bflo(u0.w); a7 += bfhi(u0.w);
        a0 += bflo(u1.x); a1 += bfhi(u1.x);
        a2 += bflo(u1.y); a3 += bfhi(u1.y);
        a4 += bflo(u1.z); a5 += bfhi(u1.z);
        a6 += bflo(u1.w); a7 += bfhi(u1.w);
    }
#pragma unroll
    for (int m = 4; m <= 32; m <<= 1) {
        a0 += __shfl_xor(a0, m, 64); a1 += __shfl_xor(a1, m, 64);
        a2 += __shfl_xor(a2, m, 64); a3 += __shfl_xor(a3, m, 64);
        a4 += __shfl_xor(a4, m, 64); a5 += __shfl_xor(a5, m, 64);
        a6 += __shfl_xor(a6, m, 64); a7 += __shfl_xor(a7, m, 64);
    }
    if (lane < 3) {
        float inv = 1.f / (float)max(e - b, 1);
        uint4 o;
        o.x = (unsigned int)f2bf(a0 * inv) | ((unsigned int)f2bf(a1 * inv) << 16);
        o.y = (unsigned int)f2bf(a2 * inv) | ((unsigned int)f2bf(a3 * inv) << 16);
        o.z = (unsigned int)f2bf(a4 * inv) | ((unsigned int)f2bf(a5 * inv) << 16);
        o.w = (unsigned int)f2bf(a6 * inv) | ((unsigned int)f2bf(a7 * inv) << 16);
        *(uint4*)(A1w + (size_t)node * 32 + 12 + lane * 4) = o;
    }
}

// agg2: gather 128B h rows, 8 lanes/edge, 8 slots x 4 loads = 32 edges/iter
__global__ __launch_bounds__(256) void k_agg2(const unsigned int* __restrict__ A2u,
                                              const int* __restrict__ rowptr,
                                              const int* __restrict__ srcs,
                                              unsigned int* __restrict__ A2w, int N) {
    int node = (blockIdx.x * 256 + threadIdx.x) >> 6;
    int lane = threadIdx.x & 63;
    if (node >= N) return;
    int b = rowptr[node], e = rowptr[node + 1];
    int grp = lane >> 3;    // 0..7 edge slot
    int sub = lane & 7;     // 16B chunk of 128B h payload
    float a0 = 0.f, a1 = 0.f, a2 = 0.f, a3 = 0.f;
    float a4 = 0.f, a5 = 0.f, a6 = 0.f, a7 = 0.f;
    for (int j = b; j < e; j += 32) {
        int j0 = j + grp, j1 = j0 + 8, j2 = j0 + 16, j3 = j0 + 24;
        int s0 = srcs[j0];
        int s1 = srcs[j1];
        int s2 = srcs[j2];
        int s3 = srcs[j3];
        uint4 u0 = *(const uint4*)(A2u + (size_t)s0 * 64 + 32 + sub * 4);
        uint4 u1 = *(const uint4*)(A2u + (size_t)s1 * 64 + 32 + sub * 4);
        uint4 u2 = *(const uint4*)(A2u + (size_t)s2 * 64 + 32 + sub * 4);
        uint4 u3 = *(const uint4*)(A2u + (size_t)s3 * 64 + 32 + sub * 4);
        if (j0 >= e) { u0.x = 0; u0.y = 0; u0.z = 0; u0.w = 0; }
        if (j1 >= e) { u1.x = 0; u1.y = 0; u1.z = 0; u1.w = 0; }
        if (j2 >= e) { u2.x = 0; u2.y = 0; u2.z = 0; u2.w = 0; }
        if (j3 >= e) { u3.x = 0; u3.y = 0; u3.z = 0; u3.w = 0; }
        a0 += bflo(u0.x); a1 += bfhi(u0.x);
        a2 += bflo(u0.y); a3 += bfhi(u0.y);
        a4 += bflo(u0.z); a5 += bfhi(u0.z);
        a6 += bflo(u0.w); a7 += bfhi(u0.w);
        a0 += bflo(u1.x); a1 += bfhi(u1.x);
        a2 += bflo(u1.y); a3 += bfhi(u1.y);
        a4 += bflo(u1.z); a5 += bfhi(u1.z);
        a6 += bflo(u1.w); a7 += bfhi(u1.w);
        a0 += bflo(u2.x); a1 += bfhi(u2.x);
        a2 += bflo(u2.y); a3 += bfhi(u2.y);
        a4 += bflo(u2.z); a5 += bfhi(u2.z);
        a6 += bflo(u2.w); a7 += bfhi(u2.w);
        a0 += bflo(u3.x); a1 += bfhi(u3.x);
        a2 += bflo(u3.y); a3 += bfhi(u3.y);
        a4 += bflo(u3.z); a5 += bfhi(u3.z);
        a6 += bflo(u3.w); a7 += bfhi(u3.w);
    }
#pragma unroll
    for (int m = 8; m <= 32; m <<= 1) {
        a0 += __shfl_xor(a0, m, 64); a1 += __shfl_xor(a1, m, 64);
        a2 += __shfl_xor(a2, m, 64); a3 += __shfl_xor(a3, m, 64);
        a4 += __shfl_xor(a4, m, 64); a5 += __shfl_xor(a5, m, 64);
        a6 += __shfl_xor(a6, m, 64); a7 += __shfl_xor(a7, m, 64);
    }
    if (lane < 8) {
        float inv = 1.f / (float)max(e - b, 1);
        uint4 o;
        o.x = (unsigned int)f2bf(a0 * inv) | ((unsigned int)f2bf(a1 * inv) << 16);
        o.y = (unsigned int)f2bf(a2 * inv) | ((unsigned int)f2bf(a3 * inv) << 16);
        o.z = (unsigned int)f2bf(a4 * inv) | ((unsigned int)f2bf(a5 * inv) << 16);
        o.w = (unsigned int)f2bf(a6 * inv) | ((unsigned int)f2bf(a7 * inv) << 16);
        *(uint4*)(A2w + (size_t)node * 64 + lane * 4) = o;
    }
}

// ---------------- MFMA GEMMs (no LDS; B^T in registers) ----------------

__global__ __launch_bounds__(256) void k_gemm1(const unsigned short* __restrict__ A1,
                                               const unsigned short* __restrict__ Bt1,
                                               const float* __restrict__ b1,
                                               unsigned short* __restrict__ A2s) {
    int wave = (blockIdx.x * 256 + threadIdx.x) >> 6;
    int lane = threadIdx.x & 63;
    int m = lane & 15, quad = lane >> 4;
    if (wave >= NSTRIPS) return;
    short8 bf[4][2];
#pragma unroll
    for (int t = 0; t < 4; t++)
#pragma unroll
        for (int s = 0; s < 2; s++)
            bf[t][s] = *(const short8*)(Bt1 + (t * 16 + m) * 64 + s * 32 + quad * 8);
    float bias[4];
#pragma unroll
    for (int t = 0; t < 4; t++) bias[t] = b1[t * 16 + m];

    int row0 = wave * 16;
    short8 a0 = *(const short8*)(A1 + (row0 + m) * 64 + quad * 8);
    short8 a1 = *(const short8*)(A1 + (row0 + m) * 64 + 32 + quad * 8);
    float4_ acc[4];
#pragma unroll
    for (int t = 0; t < 4; t++) {
        float4_ c = {0.f, 0.f, 0.f, 0.f};
        c = __builtin_amdgcn_mfma_f32_16x16x32_bf16(a0, bf[t][0], c, 0, 0, 0);
        c = __builtin_amdgcn_mfma_f32_16x16x32_bf16(a1, bf[t][1], c, 0, 0, 0);
        acc[t] = c;
    }
#pragma unroll
    for (int t = 0; t < 4; t++) {
        int col = t * 16 + m;
#pragma unroll
        for (int r = 0; r < 4; r++) {
            int row = row0 + quad * 4 + r;
            float v = fmaxf(acc[t][r] + bias[t], 0.f);
            A2s[row * 128 + 64 + col] = f2bf(v);
        }
    }
}

__global__ __launch_bounds__(256) void k_gemm2(const unsigned short* __restrict__ Bt2,
                                               const float* __restrict__ bias2,
                                               unsigned short* A2s,
                                               float* logits) {
    int wave = (blockIdx.x * 256 + threadIdx.x) >> 6;
    int lane = threadIdx.x & 63;
    int m = lane & 15, quad = lane >> 4;
    if (wave >= NSTRIPS) return;
    short8 bf[5][4];
#pragma unroll
    for (int t = 0; t < 5; t++)
#pragma unroll
        for (int s = 0; s < 4; s++)
            bf[t][s] = *(const short8*)(Bt2 + (t * 16 + m) * 128 + s * 32 + quad * 8);
    float bias[5];
#pragma unroll
    for (int t = 0; t < 5; t++) bias[t] = bias2[t * 16 + m];

    int row0 = wave * 16;
    short8 a[4];
#pragma unroll
    for (int s = 0; s < 4; s++)
        a[s] = *(const short8*)(A2s + (row0 + m) * 128 + s * 32 + quad * 8);
    float4_ acc[5];
#pragma unroll
    for (int t = 0; t < 5; t++) {
        float4_ c = {0.f, 0.f, 0.f, 0.f};
#pragma unroll
        for (int s = 0; s < 4; s++)
            c = __builtin_amdgcn_mfma_f32_16x16x32_bf16(a[s], bf[t][s], c, 0, 0, 0);
        acc[t] = c;
    }
    float* embp = (float*)A2s;
#pragma unroll
    for (int t = 0; t < 4; t++) {
#pragma unroll
        for (int r = 0; r < 4; r++) {
            int row = row0 + quad * 4 + r;
            embp[row * 64 + t * 16 + m] = acc[t][r] + bias[t];
        }
    }
#pragma unroll
    for (int r = 0; r < 4; r++) {
        int row = row0 + quad * 4 + r;
        logits[row * 16 + m] = acc[4][r] + bias[4];
    }
}

// ---------------- launch ----------------

extern "C" void kernel_launch(void* const* d_in, const int* in_sizes, int n_in,
                              void* d_out, int out_size, void* d_ws, size_t ws_size,
                              hipStream_t stream) {
    const float* x = (const float*)d_in[0];
    const int* edge = (const int*)d_in[1];
    const int* srcIdx = edge;
    const int* dstIdx = edge + N_EDGES;
    const float* W1l = (const float*)d_in[2];
    const float* b1  = (const float*)d_in[3];
    const float* W1r = (const float*)d_in[4];
    const float* W2l = (const float*)d_in[5];
    const float* b2  = (const float*)d_in[6];
    const float* W2r = (const float*)d_in[7];
    const float* Wc  = (const float*)d_in[8];
    const float* bc  = (const float*)d_in[9];

    float* logits = (float*)d_out;
    unsigned short* A2s = (unsigned short*)((float*)d_out + (size_t)N_NODES * N_CLASSES);
    unsigned int* A2u = (unsigned int*)A2s;

    char* w = (char*)d_ws;
    auto carve = [&](size_t bytes) {
        char* p = w;
        w += (bytes + 255) & ~(size_t)255;
        return p;
    };
    int* rowptr          = (int*)carve((N_NODES + 1) * sizeof(int));
    int* srcs            = (int*)carve((size_t)(N_EDGES + 32) * sizeof(int));
    unsigned int* A1u    = (unsigned int*)carve((size_t)N_NODES * 32 * sizeof(unsigned int));
    unsigned int* XCu    = (unsigned int*)carve((size_t)N_NODES * 16 * sizeof(unsigned int));
    int* bucketCnt       = (int*)carve(NBUCK * sizeof(int));
    int* bucketBase      = (int*)carve((NBUCK + 1) * sizeof(int));
    int* bucketFill      = (int*)carve(NBUCK * sizeof(int));
    unsigned short* Bt1  = (unsigned short*)carve(64 * 64 * sizeof(unsigned short));
    unsigned short* Bt2  = (unsigned short*)carve(80 * 128 * sizeof(unsigned short));
    float* bias2         = (float*)carve(80 * sizeof(float));

    unsigned int* pedges = A1u;   // consumed by k_bucket before k_castx writes A1
    unsigned short* A1s = (unsigned short*)A1u;

    k_prep<<<1, 256, 0, stream>>>(W1l, W1r, W2l, W2r, Wc, b2, bc, Bt1, Bt2, bias2);

    hipMemsetAsync(bucketCnt, 0, NBUCK * sizeof(int), stream);
    k_phist<<<256, 256, 0, stream>>>(dstIdx, bucketCnt, N_EDGES);
    k_scanb<<<1, 512, 0, stream>>>(bucketCnt, bucketBase, bucketFill, srcs, N_EDGES);
    int pbl = (N_EDGES + CHUNK - 1) / CHUNK;
    k_part<<<pbl, 256, 0, stream>>>(srcIdx, dstIdx, bucketFill, pedges, N_EDGES);
    k_bucket<<<NBUCK, 256, 0, stream>>>(pedges, bucketBase, rowptr, srcs,
                                        N_NODES, N_EDGES);

    k_castx<<<(N_NODES * 32 + 255) / 256, 256, 0, stream>>>(x, A1u, XCu);
    k_agg1<<<(N_NODES * 64 + 255) / 256, 256, 0, stream>>>(XCu, rowptr, srcs, A1u, N_NODES);
    k_gemm1<<<(NSTRIPS + 3) / 4, 256, 0, stream>>>(A1s, Bt1, b1, A2s);
    k_agg2<<<(N_NODES * 64 + 255) / 256, 256, 0, stream>>>(A2u, rowptr, srcs, A2u, N_NODES);
    k_gemm2<<<(NSTRIPS + 3) / 4, 256, 0, stream>>>(Bt2, bias2, A2s, logits);
}

// Round 6
// 324.845 us; speedup vs baseline: 3.1740x; 1.0899x over previous
//
#include <hip/hip_runtime.h>

#define N_NODES 100000
#define N_EDGES 3200000
#define IN_CH 24
#define HIDDEN 64
#define N_CLASSES 16

#define NBUCK 391      // ceil(N_NODES / 256)
#define CHUNK 8192     // edges per partition block
#define NSTRIPS (N_NODES / 16)   // 6250 exact

typedef __attribute__((ext_vector_type(8))) short short8;
typedef __attribute__((ext_vector_type(4))) float float4_;

__device__ __forceinline__ unsigned short f2bf(float f) {
    union { float f; unsigned int u; } v; v.f = f;
    unsigned int u = v.u;
    return (unsigned short)((u + 0x7FFFu + ((u >> 16) & 1u)) >> 16);
}
__device__ __forceinline__ float bflo(unsigned int u) {
    union { unsigned int u; float f; } v; v.u = u << 16; return v.f;
}
__device__ __forceinline__ float bfhi(unsigned int u) {
    union { unsigned int u; float f; } v; v.u = u & 0xFFFF0000u; return v.f;
}

// ---------------- CSR build (two-level partition; 1024-thread blocks) ------

__global__ __launch_bounds__(1024) void k_phist(const int* __restrict__ dst,
                                                int* __restrict__ bucketCnt, int E) {
    __shared__ int hist[NBUCK];
    int t = threadIdx.x;
    for (int i = t; i < NBUCK; i += 1024) hist[i] = 0;
    __syncthreads();
    for (int e = blockIdx.x * 1024 + t; e < E; e += 1024 * gridDim.x)
        atomicAdd(&hist[dst[e] >> 8], 1);
    __syncthreads();
    for (int i = t; i < NBUCK; i += 1024)
        if (hist[i]) atomicAdd(&bucketCnt[i], hist[i]);
}

__global__ __launch_bounds__(512) void k_scanb(const int* __restrict__ bucketCnt,
                                               int* __restrict__ bucketBase,
                                               int* __restrict__ bucketFill,
                                               int* __restrict__ srcs, int E) {
    __shared__ int lds[512];
    int t = threadIdx.x;
    int c = (t < NBUCK) ? bucketCnt[t] : 0;
    int val = c;
    lds[t] = val;
    __syncthreads();
    for (int off = 1; off < 512; off <<= 1) {
        int v = (t >= off) ? lds[t - off] : 0;
        __syncthreads();
        val += v;
        lds[t] = val;
        __syncthreads();
    }
    if (t < NBUCK) {
        int ex = val - c;
        bucketBase[t] = ex;
        bucketFill[t] = ex;
    }
    if (t == 0) bucketBase[NBUCK] = E;
    // zero-fill srcs slack tail so OOB-masked gathers read node 0 (valid mem)
    if (t < 32) srcs[E + t] = 0;
}

__global__ __launch_bounds__(1024) void k_part(const int* __restrict__ src,
                                               const int* __restrict__ dst,
                                               int* __restrict__ bucketFill,
                                               unsigned int* __restrict__ pedges, int E) {
    __shared__ int cntL[NBUCK];
    __shared__ int baseL[NBUCK];
    int t = threadIdx.x;
    int cbeg = blockIdx.x * CHUNK;
    int cend = min(cbeg + CHUNK, E);
    for (int i = t; i < NBUCK; i += 1024) cntL[i] = 0;
    __syncthreads();
    for (int j = cbeg + t; j < cend; j += 1024)
        atomicAdd(&cntL[dst[j] >> 8], 1);
    __syncthreads();
    for (int i = t; i < NBUCK; i += 1024) {
        int c = cntL[i];
        if (c) baseL[i] = atomicAdd(&bucketFill[i], c);
        cntL[i] = 0;
    }
    __syncthreads();
    for (int j = cbeg + t; j < cend; j += 1024) {
        int d = dst[j], s = src[j];
        int bk = d >> 8;
        int r = atomicAdd(&cntL[bk], 1);
        pedges[baseL[bk] + r] = ((unsigned int)(d & 255) << 17) | (unsigned int)s;
    }
}

__global__ __launch_bounds__(1024) void k_bucket(const unsigned int* __restrict__ pedges,
                                                 const int* __restrict__ bucketBase,
                                                 int* __restrict__ rowptr,
                                                 int* __restrict__ srcs, int N, int E) {
    __shared__ int ncnt[256];
    __shared__ int scanb[256];
    int b = blockIdx.x;
    int t = threadIdx.x;
    int eb = bucketBase[b], ee = bucketBase[b + 1];
    if (t < 256) ncnt[t] = 0;
    __syncthreads();
    for (int j = eb + t; j < ee; j += 1024) {
        unsigned int v = pedges[j];
        atomicAdd(&ncnt[v >> 17], 1);
    }
    __syncthreads();
    int myc = (t < 256) ? ncnt[t] : 0;
    int val = myc;
    if (t < 256) scanb[t] = val;
    __syncthreads();
    for (int off = 1; off < 256; off <<= 1) {
        int v2 = (t >= off && t < 256) ? scanb[t - off] : 0;
        __syncthreads();
        if (t < 256) { val += v2; scanb[t] = val; }
        __syncthreads();
    }
    int mybase = val - myc;
    int node = b * 256 + t;
    if (t < 256 && node < N) rowptr[node] = eb + mybase;
    if (b == 0 && t == 0) rowptr[N] = E;
    if (t < 256) { scanb[t] = mybase; ncnt[t] = 0; }
    __syncthreads();
    for (int j = eb + t; j < ee; j += 1024) {
        unsigned int v = pedges[j];
        int nl = v >> 17;
        int r = atomicAdd(&ncnt[nl], 1);
        srcs[eb + scanb[nl] + r] = (int)(v & 0x1FFFF);
    }
}

// ---------------- weight prep ----------------

__global__ __launch_bounds__(256) void k_prep(const float* __restrict__ W1l,
                                              const float* __restrict__ W1r,
                                              const float* __restrict__ W2l,
                                              const float* __restrict__ W2r,
                                              const float* __restrict__ Wc,
                                              const float* __restrict__ b2,
                                              const float* __restrict__ bc,
                                              unsigned short* __restrict__ Bt1,
                                              unsigned short* __restrict__ Bt2,
                                              float* __restrict__ bias2) {
    int t = threadIdx.x;
    for (int i = t; i < 64 * 64; i += 256) {
        int o = i >> 6, k = i & 63;
        float v = (k < 24) ? W1r[o * 24 + k] : ((k < 48) ? W1l[o * 24 + k - 24] : 0.f);
        Bt1[i] = f2bf(v);
    }
    for (int i = t; i < 64 * 128; i += 256) {
        int o = i >> 7, k = i & 127;
        float v = (k < 64) ? W2l[o * 64 + k] : W2r[o * 64 + k - 64];
        Bt2[i] = f2bf(v);
    }
    for (int i = t; i < 16 * 128; i += 256) {
        int c = i >> 7, k = i & 127;
        const float* M = (k < 64) ? W2l : W2r;
        int kk = k & 63;
        float s = 0.f;
        for (int j = 0; j < 64; j++) s += Wc[c * 64 + j] * M[j * 64 + kk];
        Bt2[(64 + c) * 128 + k] = f2bf(s);
    }
    for (int i = t; i < 80; i += 256) {
        if (i < 64) bias2[i] = b2[i];
        else {
            int c = i - 64;
            float s = bc[c];
            for (int j = 0; j < 64; j++) s += Wc[c * 64 + j] * b2[j];
            bias2[i] = s;
        }
    }
}

// x fp32 -> A1 rows (128B: x|mean|pad) AND compact xc rows (64B: x|pad)
__global__ __launch_bounds__(256) void k_castx(const float* __restrict__ x,
                                               unsigned int* __restrict__ A1u,
                                               unsigned int* __restrict__ XCu) {
    int gid = blockIdx.x * 256 + threadIdx.x;
    if (gid >= N_NODES * 32) return;
    int n = gid >> 5, kp = gid & 31;
    unsigned int out = 0;
    if (kp < 12) {
        const float2 v = *(const float2*)(x + n * 24 + kp * 2);
        out = (unsigned int)f2bf(v.x) | ((unsigned int)f2bf(v.y) << 16);
    }
    A1u[gid] = out;
    if (kp < 16) XCu[n * 16 + kp] = out;
}

// ---------------- aggregations: masked uint4 gathers, deep pipeline --------

// agg1: gather 64B xc rows, 4 lanes/edge, 16 slots x 2 loads = 32 edges/iter
__global__ __launch_bounds__(256) void k_agg1(const unsigned int* __restrict__ XCu,
                                              const int* __restrict__ rowptr,
                                              const int* __restrict__ srcs,
                                              unsigned int* __restrict__ A1w, int N) {
    int node = (blockIdx.x * 256 + threadIdx.x) >> 6;
    int lane = threadIdx.x & 63;
    if (node >= N) return;
    int b = rowptr[node], e = rowptr[node + 1];
    int grp = lane >> 2;    // 0..15 edge slot
    int sub = lane & 3;     // 16B chunk of 64B row
    float a0 = 0.f, a1 = 0.f, a2 = 0.f, a3 = 0.f;
    float a4 = 0.f, a5 = 0.f, a6 = 0.f, a7 = 0.f;
    for (int j = b; j < e; j += 32) {
        int j0 = j + grp, j1 = j0 + 16;
        int s0 = srcs[j0];
        int s1 = srcs[j1];
        uint4 u0 = *(const uint4*)(XCu + (size_t)s0 * 16 + sub * 4);
        uint4 u1 = *(const uint4*)(XCu + (size_t)s1 * 16 + sub * 4);
        if (j0 >= e) { u0.x = 0; u0.y = 0; u0.z = 0; u0.w = 0; }
        if (j1 >= e) { u1.x = 0; u1.y = 0; u1.z = 0; u1.w = 0; }
        a0 += bflo(u0.x); a1 += bfhi(u0.x);
        a2 += bflo(u0.y); a3 += bfhi(u0.y);
        a4 += bflo(u0.z); a5 += bfhi(u0.z);
        a6 += bflo(u0.w); a7 += bfhi(u0.w);
        a0 += bflo(u1.x); a1 += bfhi(u1.x);
        a2 += bflo(u1.y); a3 += bfhi(u1.y);
        a4 += bflo(u1.z); a5 += bfhi(u1.z);
        a6 += bflo(u1.w); a7 += bfhi(u1.w);
    }
#pragma unroll
    for (int m = 4; m <= 32; m <<= 1) {
        a0 += __shfl_xor(a0, m, 64); a1 += __shfl_xor(a1, m, 64);
        a2 += __shfl_xor(a2, m, 64); a3 += __shfl_xor(a3, m, 64);
        a4 += __shfl_xor(a4, m, 64); a5 += __shfl_xor(a5, m, 64);
        a6 += __shfl_xor(a6, m, 64); a7 += __shfl_xor(a7, m, 64);
    }
    if (lane < 3) {
        float inv = 1.f / (float)max(e - b, 1);
        uint4 o;
        o.x = (unsigned int)f2bf(a0 * inv) | ((unsigned int)f2bf(a1 * inv) << 16);
        o.y = (unsigned int)f2bf(a2 * inv) | ((unsigned int)f2bf(a3 * inv) << 16);
        o.z = (unsigned int)f2bf(a4 * inv) | ((unsigned int)f2bf(a5 * inv) << 16);
        o.w = (unsigned int)f2bf(a6 * inv) | ((unsigned int)f2bf(a7 * inv) << 16);
        *(uint4*)(A1w + (size_t)node * 32 + 12 + lane * 4) = o;
    }
}

// agg2: gather 128B h rows, 8 lanes/edge, 8 slots x 4 loads = 32 edges/iter
__global__ __launch_bounds__(256) void k_agg2(const unsigned int* __restrict__ A2u,
                                              const int* __restrict__ rowptr,
                                              const int* __restrict__ srcs,
                                              unsigned int* __restrict__ A2w, int N) {
    int node = (blockIdx.x * 256 + threadIdx.x) >> 6;
    int lane = threadIdx.x & 63;
    if (node >= N) return;
    int b = rowptr[node], e = rowptr[node + 1];
    int grp = lane >> 3;    // 0..7 edge slot
    int sub = lane & 7;     // 16B chunk of 128B h payload
    float a0 = 0.f, a1 = 0.f, a2 = 0.f, a3 = 0.f;
    float a4 = 0.f, a5 = 0.f, a6 = 0.f, a7 = 0.f;
    for (int j = b; j < e; j += 32) {
        int j0 = j + grp, j1 = j0 + 8, j2 = j0 + 16, j3 = j0 + 24;
        int s0 = srcs[j0];
        int s1 = srcs[j1];
        int s2 = srcs[j2];
        int s3 = srcs[j3];
        uint4 u0 = *(const uint4*)(A2u + (size_t)s0 * 64 + 32 + sub * 4);
        uint4 u1 = *(const uint4*)(A2u + (size_t)s1 * 64 + 32 + sub * 4);
        uint4 u2 = *(const uint4*)(A2u + (size_t)s2 * 64 + 32 + sub * 4);
        uint4 u3 = *(const uint4*)(A2u + (size_t)s3 * 64 + 32 + sub * 4);
        if (j0 >= e) { u0.x = 0; u0.y = 0; u0.z = 0; u0.w = 0; }
        if (j1 >= e) { u1.x = 0; u1.y = 0; u1.z = 0; u1.w = 0; }
        if (j2 >= e) { u2.x = 0; u2.y = 0; u2.z = 0; u2.w = 0; }
        if (j3 >= e) { u3.x = 0; u3.y = 0; u3.z = 0; u3.w = 0; }
        a0 += bflo(u0.x); a1 += bfhi(u0.x);
        a2 += bflo(u0.y); a3 += bfhi(u0.y);
        a4 += bflo(u0.z); a5 += bfhi(u0.z);
        a6 += bflo(u0.w); a7 += bfhi(u0.w);
        a0 += bflo(u1.x); a1 += bfhi(u1.x);
        a2 += bflo(u1.y); a3 += bfhi(u1.y);
        a4 += bflo(u1.z); a5 += bfhi(u1.z);
        a6 += bflo(u1.w); a7 += bfhi(u1.w);
        a0 += bflo(u2.x); a1 += bfhi(u2.x);
        a2 += bflo(u2.y); a3 += bfhi(u2.y);
        a4 += bflo(u2.z); a5 += bfhi(u2.z);
        a6 += bflo(u2.w); a7 += bfhi(u2.w);
        a0 += bflo(u3.x); a1 += bfhi(u3.x);
        a2 += bflo(u3.y); a3 += bfhi(u3.y);
        a4 += bflo(u3.z); a5 += bfhi(u3.z);
        a6 += bflo(u3.w); a7 += bfhi(u3.w);
    }
#pragma unroll
    for (int m = 8; m <= 32; m <<= 1) {
        a0 += __shfl_xor(a0, m, 64); a1 += __shfl_xor(a1, m, 64);
        a2 += __shfl_xor(a2, m, 64); a3 += __shfl_xor(a3, m, 64);
        a4 += __shfl_xor(a4, m, 64); a5 += __shfl_xor(a5, m, 64);
        a6 += __shfl_xor(a6, m, 64); a7 += __shfl_xor(a7, m, 64);
    }
    if (lane < 8) {
        float inv = 1.f / (float)max(e - b, 1);
        uint4 o;
        o.x = (unsigned int)f2bf(a0 * inv) | ((unsigned int)f2bf(a1 * inv) << 16);
        o.y = (unsigned int)f2bf(a2 * inv) | ((unsigned int)f2bf(a3 * inv) << 16);
        o.z = (unsigned int)f2bf(a4 * inv) | ((unsigned int)f2bf(a5 * inv) << 16);
        o.w = (unsigned int)f2bf(a6 * inv) | ((unsigned int)f2bf(a7 * inv) << 16);
        *(uint4*)(A2w + (size_t)node * 64 + lane * 4) = o;
    }
}

// ---------------- MFMA GEMMs (no LDS; B^T in registers) ----------------

__global__ __launch_bounds__(256) void k_gemm1(const unsigned short* __restrict__ A1,
                                               const unsigned short* __restrict__ Bt1,
                                               const float* __restrict__ b1,
                                               unsigned short* __restrict__ A2s) {
    int wave = (blockIdx.x * 256 + threadIdx.x) >> 6;
    int lane = threadIdx.x & 63;
    int m = lane & 15, quad = lane >> 4;
    if (wave >= NSTRIPS) return;
    short8 bf[4][2];
#pragma unroll
    for (int t = 0; t < 4; t++)
#pragma unroll
        for (int s = 0; s < 2; s++)
            bf[t][s] = *(const short8*)(Bt1 + (t * 16 + m) * 64 + s * 32 + quad * 8);
    float bias[4];
#pragma unroll
    for (int t = 0; t < 4; t++) bias[t] = b1[t * 16 + m];

    int row0 = wave * 16;
    short8 a0 = *(const short8*)(A1 + (row0 + m) * 64 + quad * 8);
    short8 a1 = *(const short8*)(A1 + (row0 + m) * 64 + 32 + quad * 8);
    float4_ acc[4];
#pragma unroll
    for (int t = 0; t < 4; t++) {
        float4_ c = {0.f, 0.f, 0.f, 0.f};
        c = __builtin_amdgcn_mfma_f32_16x16x32_bf16(a0, bf[t][0], c, 0, 0, 0);
        c = __builtin_amdgcn_mfma_f32_16x16x32_bf16(a1, bf[t][1], c, 0, 0, 0);
        acc[t] = c;
    }
#pragma unroll
    for (int t = 0; t < 4; t++) {
        int col = t * 16 + m;
#pragma unroll
        for (int r = 0; r < 4; r++) {
            int row = row0 + quad * 4 + r;
            float v = fmaxf(acc[t][r] + bias[t], 0.f);
            A2s[row * 128 + 64 + col] = f2bf(v);
        }
    }
}

__global__ __launch_bounds__(256) void k_gemm2(const unsigned short* __restrict__ Bt2,
                                               const float* __restrict__ bias2,
                                               unsigned short* A2s,
                                               float* logits) {
    int wave = (blockIdx.x * 256 + threadIdx.x) >> 6;
    int lane = threadIdx.x & 63;
    int m = lane & 15, quad = lane >> 4;
    if (wave >= NSTRIPS) return;
    short8 bf[5][4];
#pragma unroll
    for (int t = 0; t < 5; t++)
#pragma unroll
        for (int s = 0; s < 4; s++)
            bf[t][s] = *(const short8*)(Bt2 + (t * 16 + m) * 128 + s * 32 + quad * 8);
    float bias[5];
#pragma unroll
    for (int t = 0; t < 5; t++) bias[t] = bias2[t * 16 + m];

    int row0 = wave * 16;
    short8 a[4];
#pragma unroll
    for (int s = 0; s < 4; s++)
        a[s] = *(const short8*)(A2s + (row0 + m) * 128 + s * 32 + quad * 8);
    float4_ acc[5];
#pragma unroll
    for (int t = 0; t < 5; t++) {
        float4_ c = {0.f, 0.f, 0.f, 0.f};
#pragma unroll
        for (int s = 0; s < 4; s++)
            c = __builtin_amdgcn_mfma_f32_16x16x32_bf16(a[s], bf[t][s], c, 0, 0, 0);
        acc[t] = c;
    }
    float* embp = (float*)A2s;
#pragma unroll
    for (int t = 0; t < 4; t++) {
#pragma unroll
        for (int r = 0; r < 4; r++) {
            int row = row0 + quad * 4 + r;
            embp[row * 64 + t * 16 + m] = acc[t][r] + bias[t];
        }
    }
#pragma unroll
    for (int r = 0; r < 4; r++) {
        int row = row0 + quad * 4 + r;
        logits[row * 16 + m] = acc[4][r] + bias[4];
    }
}

// ---------------- launch ----------------

extern "C" void kernel_launch(void* const* d_in, const int* in_sizes, int n_in,
                              void* d_out, int out_size, void* d_ws, size_t ws_size,
                              hipStream_t stream) {
    const float* x = (const float*)d_in[0];
    const int* edge = (const int*)d_in[1];
    const int* srcIdx = edge;
    const int* dstIdx = edge + N_EDGES;
    const float* W1l = (const float*)d_in[2];
    const float* b1  = (const float*)d_in[3];
    const float* W1r = (const float*)d_in[4];
    const float* W2l = (const float*)d_in[5];
    const float* b2  = (const float*)d_in[6];
    const float* W2r = (const float*)d_in[7];
    const float* Wc  = (const float*)d_in[8];
    const float* bc  = (const float*)d_in[9];

    float* logits = (float*)d_out;
    unsigned short* A2s = (unsigned short*)((float*)d_out + (size_t)N_NODES * N_CLASSES);
    unsigned int* A2u = (unsigned int*)A2s;

    char* w = (char*)d_ws;
    auto carve = [&](size_t bytes) {
        char* p = w;
        w += (bytes + 255) & ~(size_t)255;
        return p;
    };
    int* rowptr          = (int*)carve((N_NODES + 1) * sizeof(int));
    int* srcs            = (int*)carve((size_t)(N_EDGES + 32) * sizeof(int));
    unsigned int* A1u    = (unsigned int*)carve((size_t)N_NODES * 32 * sizeof(unsigned int));
    unsigned int* XCu    = (unsigned int*)carve((size_t)N_NODES * 16 * sizeof(unsigned int));
    int* bucketCnt       = (int*)carve(NBUCK * sizeof(int));
    int* bucketBase      = (int*)carve((NBUCK + 1) * sizeof(int));
    int* bucketFill      = (int*)carve(NBUCK * sizeof(int));
    unsigned short* Bt1  = (unsigned short*)carve(64 * 64 * sizeof(unsigned short));
    unsigned short* Bt2  = (unsigned short*)carve(80 * 128 * sizeof(unsigned short));
    float* bias2         = (float*)carve(80 * sizeof(float));

    unsigned int* pedges = A1u;   // consumed by k_bucket before k_castx writes A1
    unsigned short* A1s = (unsigned short*)A1u;

    k_prep<<<1, 256, 0, stream>>>(W1l, W1r, W2l, W2r, Wc, b2, bc, Bt1, Bt2, bias2);

    hipMemsetAsync(bucketCnt, 0, NBUCK * sizeof(int), stream);
    k_phist<<<512, 1024, 0, stream>>>(dstIdx, bucketCnt, N_EDGES);
    k_scanb<<<1, 512, 0, stream>>>(bucketCnt, bucketBase, bucketFill, srcs, N_EDGES);
    int pbl = (N_EDGES + CHUNK - 1) / CHUNK;
    k_part<<<pbl, 1024, 0, stream>>>(srcIdx, dstIdx, bucketFill, pedges, N_EDGES);
    k_bucket<<<NBUCK, 1024, 0, stream>>>(pedges, bucketBase, rowptr, srcs,
                                         N_NODES, N_EDGES);

    k_castx<<<(N_NODES * 32 + 255) / 256, 256, 0, stream>>>(x, A1u, XCu);
    k_agg1<<<(N_NODES * 64 + 255) / 256, 256, 0, stream>>>(XCu, rowptr, srcs, A1u, N_NODES);
    k_gemm1<<<(NSTRIPS + 3) / 4, 256, 0, stream>>>(A1s, Bt1, b1, A2s);
    k_agg2<<<(N_NODES * 64 + 255) / 256, 256, 0, stream>>>(A2u, rowptr, srcs, A2u, N_NODES);
    k_gemm2<<<(NSTRIPS + 3) / 4, 256, 0, stream>>>(Bt2, bias2, A2s, logits);
}

// Round 8
// 318.883 us; speedup vs baseline: 3.2333x; 1.0187x over previous
//
#include <hip/hip_runtime.h>

#define N_NODES 100000
#define N_EDGES 3200000
#define IN_CH 24
#define HIDDEN 64
#define N_CLASSES 16

#define NBUCK 782       // ceil(N_NODES / 128), 128-node buckets
#define NCHUNK 512      // partition chunks (E = 512 * 6250 exactly)
#define CHUNK2 6250
#define NSTRIPS (N_NODES / 16)   // 6250 exact

typedef __attribute__((ext_vector_type(8))) short short8;
typedef __attribute__((ext_vector_type(4))) float float4_;
typedef __attribute__((ext_vector_type(2))) float float2v;

__device__ __forceinline__ unsigned short f2bf(float f) {
    union { float f; unsigned int u; } v; v.f = f;
    unsigned int u = v.u;
    return (unsigned short)((u + 0x7FFFu + ((u >> 16) & 1u)) >> 16);
}
__device__ __forceinline__ float bflo(unsigned int u) {
    union { unsigned int u; float f; } v; v.u = u << 16; return v.f;
}
__device__ __forceinline__ float bfhi(unsigned int u) {
    union { unsigned int u; float f; } v; v.u = u & 0xFFFF0000u; return v.f;
}
__device__ __forceinline__ void accum(float2v* A, uint4 u) {
    float2v t0; t0.x = bflo(u.x); t0.y = bfhi(u.x); A[0] += t0;
    float2v t1; t1.x = bflo(u.y); t1.y = bfhi(u.y); A[1] += t1;
    float2v t2; t2.x = bflo(u.z); t2.y = bfhi(u.z); A[2] += t2;
    float2v t3; t3.x = bflo(u.w); t3.y = bfhi(u.w); A[3] += t3;
}

// ---------------- CSR build (two-level partition) ----------------

__global__ __launch_bounds__(1024) void k_phist(const int* __restrict__ dst,
                                                int* __restrict__ bucketCnt) {
    __shared__ int hist[NBUCK];
    int t = threadIdx.x;
    int cbeg = blockIdx.x * CHUNK2;
    for (int i = t; i < NBUCK; i += 1024) hist[i] = 0;
    __syncthreads();
#pragma unroll
    for (int k = 0; k < 7; k++) {
        int o = k * 1024 + t;
        if (o < CHUNK2) atomicAdd(&hist[dst[cbeg + o] >> 7], 1);
    }
    __syncthreads();
    for (int i = t; i < NBUCK; i += 1024)
        if (hist[i]) atomicAdd(&bucketCnt[i], hist[i]);
}

__global__ __launch_bounds__(1024) void k_scanb(const int* __restrict__ bucketCnt,
                                                int* __restrict__ bucketBase,
                                                int* __restrict__ bucketFill,
                                                int* __restrict__ srcs, int E) {
    __shared__ int lds[1024];
    int t = threadIdx.x;
    int c = (t < NBUCK) ? bucketCnt[t] : 0;
    int val = c;
    lds[t] = val;
    __syncthreads();
    for (int off = 1; off < 1024; off <<= 1) {
        int v = (t >= off) ? lds[t - off] : 0;
        __syncthreads();
        val += v;
        lds[t] = val;
        __syncthreads();
    }
    if (t < NBUCK) {
        int ex = val - c;
        bucketBase[t] = ex;
        bucketFill[t] = ex;
    }
    if (t == 0) bucketBase[NBUCK] = E;
    if (t < 32) srcs[E + t] = 0;   // zero tail for masked gathers
}

// register-stash partition: src/dst read ONCE per edge
__global__ __launch_bounds__(1024) void k_part(const int* __restrict__ src,
                                               const int* __restrict__ dst,
                                               int* __restrict__ bucketFill,
                                               unsigned int* __restrict__ pedges) {
    __shared__ int cntL[NBUCK];
    __shared__ int baseL[NBUCK];
    int t = threadIdx.x;
    int cbeg = blockIdx.x * CHUNK2;
    int d[7], s[7];
#pragma unroll
    for (int k = 0; k < 7; k++) {
        int o = k * 1024 + t;
        bool ok = o < CHUNK2;
        d[k] = ok ? dst[cbeg + o] : -1;
        s[k] = ok ? src[cbeg + o] : 0;
    }
    for (int i = t; i < NBUCK; i += 1024) cntL[i] = 0;
    __syncthreads();
#pragma unroll
    for (int k = 0; k < 7; k++)
        if (d[k] >= 0) atomicAdd(&cntL[d[k] >> 7], 1);
    __syncthreads();
    for (int i = t; i < NBUCK; i += 1024) {
        int c = cntL[i];
        if (c) baseL[i] = atomicAdd(&bucketFill[i], c);
        cntL[i] = 0;
    }
    __syncthreads();
#pragma unroll
    for (int k = 0; k < 7; k++)
        if (d[k] >= 0) {
            int bk = d[k] >> 7;
            int r = atomicAdd(&cntL[bk], 1);
            pedges[baseL[bk] + r] = ((unsigned int)(d[k] & 127) << 17) | (unsigned int)s[k];
        }
}

// per-bucket finalize, 128-node buckets, register-stashed pedges
__global__ __launch_bounds__(1024) void k_bucket(const unsigned int* __restrict__ pedges,
                                                 const int* __restrict__ bucketBase,
                                                 int* __restrict__ rowptr,
                                                 int* __restrict__ srcs, int N, int E) {
    __shared__ int ncnt[128];
    __shared__ int sps[128];
    int b = blockIdx.x;
    int t = threadIdx.x;
    int eb = bucketBase[b], ee = bucketBase[b + 1];
    int m = ee - eb;
    unsigned int v[8];
#pragma unroll
    for (int k = 0; k < 8; k++) {
        int o = k * 1024 + t;
        v[k] = (o < m) ? pedges[eb + o] : 0xFFFFFFFFu;
    }
    if (t < 128) ncnt[t] = 0;
    __syncthreads();
#pragma unroll
    for (int k = 0; k < 8; k++)
        if (v[k] != 0xFFFFFFFFu) atomicAdd(&ncnt[v[k] >> 17], 1);
    __syncthreads();
    int myc = (t < 128) ? ncnt[t] : 0;
    int val = myc;
    if (t < 128) sps[t] = val;
    __syncthreads();
    for (int off = 1; off < 128; off <<= 1) {
        int vv = (t >= off && t < 128) ? sps[t - off] : 0;
        __syncthreads();
        if (t < 128) { val += vv; sps[t] = val; }
        __syncthreads();
    }
    int mybase = val - myc;
    int node = b * 128 + t;
    if (t < 128 && node < N) rowptr[node] = eb + mybase;
    if (b == 0 && t == 0) rowptr[N] = E;
    if (t < 128) { sps[t] = mybase; ncnt[t] = 0; }
    __syncthreads();
#pragma unroll
    for (int k = 0; k < 8; k++)
        if (v[k] != 0xFFFFFFFFu) {
            unsigned int nl = v[k] >> 17;
            int r = atomicAdd(&ncnt[nl], 1);
            srcs[eb + sps[nl] + r] = (int)(v[k] & 0x1FFFF);
        }
}

// ---------------- weight prep ----------------

__global__ __launch_bounds__(256) void k_prep(const float* __restrict__ W1l,
                                              const float* __restrict__ W1r,
                                              const float* __restrict__ W2l,
                                              const float* __restrict__ W2r,
                                              const float* __restrict__ Wc,
                                              const float* __restrict__ b2,
                                              const float* __restrict__ bc,
                                              unsigned short* __restrict__ Bt1,
                                              unsigned short* __restrict__ Bt2,
                                              float* __restrict__ bias2) {
    int t = threadIdx.x;
    for (int i = t; i < 64 * 64; i += 256) {
        int o = i >> 6, k = i & 63;
        float v = (k < 24) ? W1r[o * 24 + k] : ((k < 48) ? W1l[o * 24 + k - 24] : 0.f);
        Bt1[i] = f2bf(v);
    }
    for (int i = t; i < 64 * 128; i += 256) {
        int o = i >> 7, k = i & 127;
        float v = (k < 64) ? W2l[o * 64 + k] : W2r[o * 64 + k - 64];
        Bt2[i] = f2bf(v);
    }
    for (int i = t; i < 16 * 128; i += 256) {
        int c = i >> 7, k = i & 127;
        const float* M = (k < 64) ? W2l : W2r;
        int kk = k & 63;
        float s = 0.f;
        for (int j = 0; j < 64; j++) s += Wc[c * 64 + j] * M[j * 64 + kk];
        Bt2[(64 + c) * 128 + k] = f2bf(s);
    }
    for (int i = t; i < 80; i += 256) {
        if (i < 64) bias2[i] = b2[i];
        else {
            int c = i - 64;
            float s = bc[c];
            for (int j = 0; j < 64; j++) s += Wc[c * 64 + j] * b2[j];
            bias2[i] = s;
        }
    }
}

// x fp32 -> A1 x-zone (dwords 0..11) + packed 48B XCu rows.
// kp 12..15 ZERO the A1 pad zone (dwords 24..31): pedges aliases A1u, and
// leftover packed-edge words contain bf16 Inf/NaN bit patterns — Inf*0 != 0.
__global__ __launch_bounds__(256) void k_castx(const float* __restrict__ x,
                                               unsigned int* __restrict__ A1u,
                                               unsigned int* __restrict__ XCu) {
    int gid = blockIdx.x * 256 + threadIdx.x;
    if (gid >= N_NODES * 16) return;
    int n = gid >> 4, kp = gid & 15;
    if (kp < 12) {
        const float2 v = *(const float2*)(x + n * 24 + kp * 2);
        unsigned int out = (unsigned int)f2bf(v.x) | ((unsigned int)f2bf(v.y) << 16);
        A1u[n * 32 + kp] = out;
        XCu[n * 12 + kp] = out;
    } else {
        int p = kp - 12;   // 0..3 -> pad dwords 24..31
        uint2 z; z.x = 0u; z.y = 0u;
        *(uint2*)(A1u + n * 32 + 24 + p * 2) = z;
    }
}

// ---------------- aggregations ----------------

// agg1: gather 48B packed x rows, 4 lanes/edge, 32 edges/iter
__global__ __launch_bounds__(256) void k_agg1(const unsigned int* __restrict__ XCu,
                                              const int* __restrict__ rowptr,
                                              const int* __restrict__ srcs,
                                              unsigned int* __restrict__ A1w, int N) {
    int node = (blockIdx.x * 256 + threadIdx.x) >> 6;
    int lane = threadIdx.x & 63;
    if (node >= N) return;
    int b = rowptr[node], e = rowptr[node + 1];
    int grp = lane >> 2;
    int sub = lane & 3;
    int subc = (sub < 3) ? sub : 2;   // sub=3 duplicates chunk 2 (never reduced/stored)
    const unsigned int* basep = XCu + subc * 4;
    float2v A[4] = {{0.f, 0.f}, {0.f, 0.f}, {0.f, 0.f}, {0.f, 0.f}};
    int nfull = (e - b) & ~31;
    int j = b;
    for (; j < b + nfull; j += 32) {
        int s0 = srcs[j + grp];
        int s1 = srcs[j + 16 + grp];
        uint4 u0 = *(const uint4*)(basep + (size_t)s0 * 12);
        uint4 u1 = *(const uint4*)(basep + (size_t)s1 * 12);
        accum(A, u0);
        accum(A, u1);
    }
    if (j < e) {
        int j0 = j + grp, j1 = j0 + 16;
        int s0 = srcs[j0], s1 = srcs[j1];
        uint4 u0 = *(const uint4*)(basep + (size_t)s0 * 12);
        uint4 u1 = *(const uint4*)(basep + (size_t)s1 * 12);
        if (j0 >= e) { u0.x = 0; u0.y = 0; u0.z = 0; u0.w = 0; }
        if (j1 >= e) { u1.x = 0; u1.y = 0; u1.z = 0; u1.w = 0; }
        accum(A, u0);
        accum(A, u1);
    }
#pragma unroll
    for (int m = 4; m <= 32; m <<= 1) {
#pragma unroll
        for (int q = 0; q < 4; q++) {
            A[q].x += __shfl_xor(A[q].x, m, 64);
            A[q].y += __shfl_xor(A[q].y, m, 64);
        }
    }
    if (lane < 3) {
        float inv = 1.f / (float)max(e - b, 1);
        uint4 o;
        o.x = (unsigned int)f2bf(A[0].x * inv) | ((unsigned int)f2bf(A[0].y * inv) << 16);
        o.y = (unsigned int)f2bf(A[1].x * inv) | ((unsigned int)f2bf(A[1].y * inv) << 16);
        o.z = (unsigned int)f2bf(A[2].x * inv) | ((unsigned int)f2bf(A[2].y * inv) << 16);
        o.w = (unsigned int)f2bf(A[3].x * inv) | ((unsigned int)f2bf(A[3].y * inv) << 16);
        *(uint4*)(A1w + (size_t)node * 32 + 12 + lane * 4) = o;
    }
}

// agg2: gather 128B h rows, 8 lanes/edge, 32 edges/iter
__global__ __launch_bounds__(256) void k_agg2(const unsigned int* __restrict__ A2u,
                                              const int* __restrict__ rowptr,
                                              const int* __restrict__ srcs,
                                              unsigned int* __restrict__ A2w, int N) {
    int node = (blockIdx.x * 256 + threadIdx.x) >> 6;
    int lane = threadIdx.x & 63;
    if (node >= N) return;
    int b = rowptr[node], e = rowptr[node + 1];
    int grp = lane >> 3;
    int sub = lane & 7;
    const unsigned int* basep = A2u + 32 + sub * 4;
    float2v A[4] = {{0.f, 0.f}, {0.f, 0.f}, {0.f, 0.f}, {0.f, 0.f}};
    int nfull = (e - b) & ~31;
    int j = b;
    for (; j < b + nfull; j += 32) {
        int s0 = srcs[j + grp];
        int s1 = srcs[j + 8 + grp];
        int s2 = srcs[j + 16 + grp];
        int s3 = srcs[j + 24 + grp];
        uint4 u0 = *(const uint4*)(basep + (size_t)s0 * 64);
        uint4 u1 = *(const uint4*)(basep + (size_t)s1 * 64);
        uint4 u2 = *(const uint4*)(basep + (size_t)s2 * 64);
        uint4 u3 = *(const uint4*)(basep + (size_t)s3 * 64);
        accum(A, u0);
        accum(A, u1);
        accum(A, u2);
        accum(A, u3);
    }
    if (j < e) {
        int j0 = j + grp, j1 = j0 + 8, j2 = j0 + 16, j3 = j0 + 24;
        int s0 = srcs[j0], s1 = srcs[j1], s2 = srcs[j2], s3 = srcs[j3];
        uint4 u0 = *(const uint4*)(basep + (size_t)s0 * 64);
        uint4 u1 = *(const uint4*)(basep + (size_t)s1 * 64);
        uint4 u2 = *(const uint4*)(basep + (size_t)s2 * 64);
        uint4 u3 = *(const uint4*)(basep + (size_t)s3 * 64);
        if (j0 >= e) { u0.x = 0; u0.y = 0; u0.z = 0; u0.w = 0; }
        if (j1 >= e) { u1.x = 0; u1.y = 0; u1.z = 0; u1.w = 0; }
        if (j2 >= e) { u2.x = 0; u2.y = 0; u2.z = 0; u2.w = 0; }
        if (j3 >= e) { u3.x = 0; u3.y = 0; u3.z = 0; u3.w = 0; }
        accum(A, u0);
        accum(A, u1);
        accum(A, u2);
        accum(A, u3);
    }
#pragma unroll
    for (int m = 8; m <= 32; m <<= 1) {
#pragma unroll
        for (int q = 0; q < 4; q++) {
            A[q].x += __shfl_xor(A[q].x, m, 64);
            A[q].y += __shfl_xor(A[q].y, m, 64);
        }
    }
    if (lane < 8) {
        float inv = 1.f / (float)max(e - b, 1);
        uint4 o;
        o.x = (unsigned int)f2bf(A[0].x * inv) | ((unsigned int)f2bf(A[0].y * inv) << 16);
        o.y = (unsigned int)f2bf(A[1].x * inv) | ((unsigned int)f2bf(A[1].y * inv) << 16);
        o.z = (unsigned int)f2bf(A[2].x * inv) | ((unsigned int)f2bf(A[2].y * inv) << 16);
        o.w = (unsigned int)f2bf(A[3].x * inv) | ((unsigned int)f2bf(A[3].y * inv) << 16);
        *(uint4*)(A2w + (size_t)node * 64 + lane * 4) = o;
    }
}

// ---------------- MFMA GEMMs (no LDS; B^T in registers) ----------------

__global__ __launch_bounds__(256) void k_gemm1(const unsigned short* __restrict__ A1,
                                               const unsigned short* __restrict__ Bt1,
                                               const float* __restrict__ b1,
                                               unsigned short* __restrict__ A2s) {
    int wave = (blockIdx.x * 256 + threadIdx.x) >> 6;
    int lane = threadIdx.x & 63;
    int m = lane & 15, quad = lane >> 4;
    if (wave >= NSTRIPS) return;
    short8 bf[4][2];
#pragma unroll
    for (int t = 0; t < 4; t++)
#pragma unroll
        for (int s = 0; s < 2; s++)
            bf[t][s] = *(const short8*)(Bt1 + (t * 16 + m) * 64 + s * 32 + quad * 8);
    float bias[4];
#pragma unroll
    for (int t = 0; t < 4; t++) bias[t] = b1[t * 16 + m];

    int row0 = wave * 16;
    short8 a0 = *(const short8*)(A1 + (row0 + m) * 64 + quad * 8);
    short8 a1 = *(const short8*)(A1 + (row0 + m) * 64 + 32 + quad * 8);
    float4_ acc[4];
#pragma unroll
    for (int t = 0; t < 4; t++) {
        float4_ c = {0.f, 0.f, 0.f, 0.f};
        c = __builtin_amdgcn_mfma_f32_16x16x32_bf16(a0, bf[t][0], c, 0, 0, 0);
        c = __builtin_amdgcn_mfma_f32_16x16x32_bf16(a1, bf[t][1], c, 0, 0, 0);
        acc[t] = c;
    }
#pragma unroll
    for (int t = 0; t < 4; t++) {
        int col = t * 16 + m;
#pragma unroll
        for (int r = 0; r < 4; r++) {
            int row = row0 + quad * 4 + r;
            float v = fmaxf(acc[t][r] + bias[t], 0.f);
            A2s[row * 128 + 64 + col] = f2bf(v);
        }
    }
}

__global__ __launch_bounds__(256) void k_gemm2(const unsigned short* __restrict__ Bt2,
                                               const float* __restrict__ bias2,
                                               unsigned short* A2s,
                                               float* logits) {
    int wave = (blockIdx.x * 256 + threadIdx.x) >> 6;
    int lane = threadIdx.x & 63;
    int m = lane & 15, quad = lane >> 4;
    if (wave >= NSTRIPS) return;
    short8 bf[5][4];
#pragma unroll
    for (int t = 0; t < 5; t++)
#pragma unroll
        for (int s = 0; s < 4; s++)
            bf[t][s] = *(const short8*)(Bt2 + (t * 16 + m) * 128 + s * 32 + quad * 8);
    float bias[5];
#pragma unroll
    for (int t = 0; t < 5; t++) bias[t] = bias2[t * 16 + m];

    int row0 = wave * 16;
    short8 a[4];
#pragma unroll
    for (int s = 0; s < 4; s++)
        a[s] = *(const short8*)(A2s + (row0 + m) * 128 + s * 32 + quad * 8);
    float4_ acc[5];
#pragma unroll
    for (int t = 0; t < 5; t++) {
        float4_ c = {0.f, 0.f, 0.f, 0.f};
#pragma unroll
        for (int s = 0; s < 4; s++)
            c = __builtin_amdgcn_mfma_f32_16x16x32_bf16(a[s], bf[t][s], c, 0, 0, 0);
        acc[t] = c;
    }
    float* embp = (float*)A2s;
#pragma unroll
    for (int t = 0; t < 4; t++) {
#pragma unroll
        for (int r = 0; r < 4; r++) {
            int row = row0 + quad * 4 + r;
            embp[row * 64 + t * 16 + m] = acc[t][r] + bias[t];
        }
    }
#pragma unroll
    for (int r = 0; r < 4; r++) {
        int row = row0 + quad * 4 + r;
        logits[row * 16 + m] = acc[4][r] + bias[4];
    }
}

// ---------------- launch ----------------

extern "C" void kernel_launch(void* const* d_in, const int* in_sizes, int n_in,
                              void* d_out, int out_size, void* d_ws, size_t ws_size,
                              hipStream_t stream) {
    const float* x = (const float*)d_in[0];
    const int* edge = (const int*)d_in[1];
    const int* srcIdx = edge;
    const int* dstIdx = edge + N_EDGES;
    const float* W1l = (const float*)d_in[2];
    const float* b1  = (const float*)d_in[3];
    const float* W1r = (const float*)d_in[4];
    const float* W2l = (const float*)d_in[5];
    const float* b2  = (const float*)d_in[6];
    const float* W2r = (const float*)d_in[7];
    const float* Wc  = (const float*)d_in[8];
    const float* bc  = (const float*)d_in[9];

    float* logits = (float*)d_out;
    unsigned short* A2s = (unsigned short*)((float*)d_out + (size_t)N_NODES * N_CLASSES);
    unsigned int* A2u = (unsigned int*)A2s;

    char* w = (char*)d_ws;
    auto carve = [&](size_t bytes) {
        char* p = w;
        w += (bytes + 255) & ~(size_t)255;
        return p;
    };
    int* rowptr          = (int*)carve((N_NODES + 1) * sizeof(int));
    int* srcs            = (int*)carve((size_t)(N_EDGES + 32) * sizeof(int));
    unsigned int* A1u    = (unsigned int*)carve((size_t)N_NODES * 32 * sizeof(unsigned int));
    unsigned int* XCu    = (unsigned int*)carve((size_t)N_NODES * 12 * sizeof(unsigned int));
    int* bucketCnt       = (int*)carve(NBUCK * sizeof(int));
    int* bucketBase      = (int*)carve((NBUCK + 1) * sizeof(int));
    int* bucketFill      = (int*)carve(NBUCK * sizeof(int));
    unsigned short* Bt1  = (unsigned short*)carve(64 * 64 * sizeof(unsigned short));
    unsigned short* Bt2  = (unsigned short*)carve(80 * 128 * sizeof(unsigned short));
    float* bias2         = (float*)carve(80 * sizeof(float));

    unsigned int* pedges = A1u;   // consumed by k_bucket before k_castx writes A1
    unsigned short* A1s = (unsigned short*)A1u;

    k_prep<<<1, 256, 0, stream>>>(W1l, W1r, W2l, W2r, Wc, b2, bc, Bt1, Bt2, bias2);

    hipMemsetAsync(bucketCnt, 0, NBUCK * sizeof(int), stream);
    k_phist<<<NCHUNK, 1024, 0, stream>>>(dstIdx, bucketCnt);
    k_scanb<<<1, 1024, 0, stream>>>(bucketCnt, bucketBase, bucketFill, srcs, N_EDGES);
    k_part<<<NCHUNK, 1024, 0, stream>>>(srcIdx, dstIdx, bucketFill, pedges);
    k_bucket<<<NBUCK, 1024, 0, stream>>>(pedges, bucketBase, rowptr, srcs,
                                         N_NODES, N_EDGES);

    k_castx<<<(N_NODES * 16 + 255) / 256, 256, 0, stream>>>(x, A1u, XCu);
    k_agg1<<<(N_NODES * 64 + 255) / 256, 256, 0, stream>>>(XCu, rowptr, srcs, A1u, N_NODES);
    k_gemm1<<<(NSTRIPS + 3) / 4, 256, 0, stream>>>(A1s, Bt1, b1, A2s);
    k_agg2<<<(N_NODES * 64 + 255) / 256, 256, 0, stream>>>(A2u, rowptr, srcs, A2u, N_NODES);
    k_gemm2<<<(NSTRIPS + 3) / 4, 256, 0, stream>>>(Bt2, bias2, A2s, logits);
}

// Round 9
// 305.702 us; speedup vs baseline: 3.3727x; 1.0431x over previous
//
#include <hip/hip_runtime.h>

#define N_NODES 100000
#define N_EDGES 3200000
#define IN_CH 24
#define HIDDEN 64
#define N_CLASSES 16

#define NBUCK 782       // ceil(N_NODES / 128), 128-node buckets
#define NCHUNK 512      // partition chunks (E = 512 * 6250 exactly)
#define CHUNK2 6250
#define NSTRIPS (N_NODES / 16)   // 6250 exact

typedef __attribute__((ext_vector_type(8))) short short8;
typedef __attribute__((ext_vector_type(4))) float float4_;
typedef __attribute__((ext_vector_type(2))) float float2v;

__device__ __forceinline__ unsigned short f2bf(float f) {
    union { float f; unsigned int u; } v; v.f = f;
    unsigned int u = v.u;
    return (unsigned short)((u + 0x7FFFu + ((u >> 16) & 1u)) >> 16);
}
__device__ __forceinline__ float bflo(unsigned int u) {
    union { unsigned int u; float f; } v; v.u = u << 16; return v.f;
}
__device__ __forceinline__ float bfhi(unsigned int u) {
    union { unsigned int u; float f; } v; v.u = u & 0xFFFF0000u; return v.f;
}
// fp8 e4m3 (OCP on gfx950) pack/unpack via HW converts
__device__ __forceinline__ unsigned short pk_fp8(float a, float b) {
    return (unsigned short)(__builtin_amdgcn_cvt_pk_fp8_f32(a, b, 0, false) & 0xFFFF);
}
__device__ __forceinline__ void accum8(float2v* A, uint2 u) {
    A[0] += __builtin_amdgcn_cvt_pk_f32_fp8(u.x, false);
    A[1] += __builtin_amdgcn_cvt_pk_f32_fp8(u.x, true);
    A[2] += __builtin_amdgcn_cvt_pk_f32_fp8(u.y, false);
    A[3] += __builtin_amdgcn_cvt_pk_f32_fp8(u.y, true);
}

// ---------------- CSR build (two-level partition) ----------------

__global__ __launch_bounds__(1024) void k_phist(const int* __restrict__ dst,
                                                int* __restrict__ bucketCnt) {
    __shared__ int hist[NBUCK];
    int t = threadIdx.x;
    int cbeg = blockIdx.x * CHUNK2;
    for (int i = t; i < NBUCK; i += 1024) hist[i] = 0;
    __syncthreads();
#pragma unroll
    for (int k = 0; k < 7; k++) {
        int o = k * 1024 + t;
        if (o < CHUNK2) atomicAdd(&hist[dst[cbeg + o] >> 7], 1);
    }
    __syncthreads();
    for (int i = t; i < NBUCK; i += 1024)
        if (hist[i]) atomicAdd(&bucketCnt[i], hist[i]);
}

__global__ __launch_bounds__(1024) void k_scanb(const int* __restrict__ bucketCnt,
                                                int* __restrict__ bucketBase,
                                                int* __restrict__ bucketFill,
                                                int* __restrict__ srcs, int E) {
    __shared__ int lds[1024];
    int t = threadIdx.x;
    int c = (t < NBUCK) ? bucketCnt[t] : 0;
    int val = c;
    lds[t] = val;
    __syncthreads();
    for (int off = 1; off < 1024; off <<= 1) {
        int v = (t >= off) ? lds[t - off] : 0;
        __syncthreads();
        val += v;
        lds[t] = val;
        __syncthreads();
    }
    if (t < NBUCK) {
        int ex = val - c;
        bucketBase[t] = ex;
        bucketFill[t] = ex;
    }
    if (t == 0) bucketBase[NBUCK] = E;
    if (t < 32) srcs[E + t] = 0;   // zero tail for masked gathers
}

__global__ __launch_bounds__(1024) void k_part(const int* __restrict__ src,
                                               const int* __restrict__ dst,
                                               int* __restrict__ bucketFill,
                                               unsigned int* __restrict__ pedges) {
    __shared__ int cntL[NBUCK];
    __shared__ int baseL[NBUCK];
    int t = threadIdx.x;
    int cbeg = blockIdx.x * CHUNK2;
    int d[7], s[7];
#pragma unroll
    for (int k = 0; k < 7; k++) {
        int o = k * 1024 + t;
        bool ok = o < CHUNK2;
        d[k] = ok ? dst[cbeg + o] : -1;
        s[k] = ok ? src[cbeg + o] : 0;
    }
    for (int i = t; i < NBUCK; i += 1024) cntL[i] = 0;
    __syncthreads();
#pragma unroll
    for (int k = 0; k < 7; k++)
        if (d[k] >= 0) atomicAdd(&cntL[d[k] >> 7], 1);
    __syncthreads();
    for (int i = t; i < NBUCK; i += 1024) {
        int c = cntL[i];
        if (c) baseL[i] = atomicAdd(&bucketFill[i], c);
        cntL[i] = 0;
    }
    __syncthreads();
#pragma unroll
    for (int k = 0; k < 7; k++)
        if (d[k] >= 0) {
            int bk = d[k] >> 7;
            int r = atomicAdd(&cntL[bk], 1);
            pedges[baseL[bk] + r] = ((unsigned int)(d[k] & 127) << 17) | (unsigned int)s[k];
        }
}

__global__ __launch_bounds__(1024) void k_bucket(const unsigned int* __restrict__ pedges,
                                                 const int* __restrict__ bucketBase,
                                                 int* __restrict__ rowptr,
                                                 int* __restrict__ srcs, int N, int E) {
    __shared__ int ncnt[128];
    __shared__ int sps[128];
    int b = blockIdx.x;
    int t = threadIdx.x;
    int eb = bucketBase[b], ee = bucketBase[b + 1];
    int m = ee - eb;
    unsigned int v[8];
#pragma unroll
    for (int k = 0; k < 8; k++) {
        int o = k * 1024 + t;
        v[k] = (o < m) ? pedges[eb + o] : 0xFFFFFFFFu;
    }
    if (t < 128) ncnt[t] = 0;
    __syncthreads();
#pragma unroll
    for (int k = 0; k < 8; k++)
        if (v[k] != 0xFFFFFFFFu) atomicAdd(&ncnt[v[k] >> 17], 1);
    __syncthreads();
    int myc = (t < 128) ? ncnt[t] : 0;
    int val = myc;
    if (t < 128) sps[t] = val;
    __syncthreads();
    for (int off = 1; off < 128; off <<= 1) {
        int vv = (t >= off && t < 128) ? sps[t - off] : 0;
        __syncthreads();
        if (t < 128) { val += vv; sps[t] = val; }
        __syncthreads();
    }
    int mybase = val - myc;
    int node = b * 128 + t;
    if (t < 128 && node < N) rowptr[node] = eb + mybase;
    if (b == 0 && t == 0) rowptr[N] = E;
    if (t < 128) { sps[t] = mybase; ncnt[t] = 0; }
    __syncthreads();
#pragma unroll
    for (int k = 0; k < 8; k++)
        if (v[k] != 0xFFFFFFFFu) {
            unsigned int nl = v[k] >> 17;
            int r = atomicAdd(&ncnt[nl], 1);
            srcs[eb + sps[nl] + r] = (int)(v[k] & 0x1FFFF);
        }
}

// ---------------- weight prep ----------------

__global__ __launch_bounds__(256) void k_prep(const float* __restrict__ W1l,
                                              const float* __restrict__ W1r,
                                              const float* __restrict__ W2l,
                                              const float* __restrict__ W2r,
                                              const float* __restrict__ Wc,
                                              const float* __restrict__ b2,
                                              const float* __restrict__ bc,
                                              unsigned short* __restrict__ Bt1,
                                              unsigned short* __restrict__ Bt2,
                                              float* __restrict__ bias2) {
    int t = threadIdx.x;
    for (int i = t; i < 64 * 64; i += 256) {
        int o = i >> 6, k = i & 63;
        float v = (k < 24) ? W1r[o * 24 + k] : ((k < 48) ? W1l[o * 24 + k - 24] : 0.f);
        Bt1[i] = f2bf(v);
    }
    for (int i = t; i < 64 * 128; i += 256) {
        int o = i >> 7, k = i & 127;
        float v = (k < 64) ? W2l[o * 64 + k] : W2r[o * 64 + k - 64];
        Bt2[i] = f2bf(v);
    }
    for (int i = t; i < 16 * 128; i += 256) {
        int c = i >> 7, k = i & 127;
        const float* M = (k < 64) ? W2l : W2r;
        int kk = k & 63;
        float s = 0.f;
        for (int j = 0; j < 64; j++) s += Wc[c * 64 + j] * M[j * 64 + kk];
        Bt2[(64 + c) * 128 + k] = f2bf(s);
    }
    for (int i = t; i < 80; i += 256) {
        if (i < 64) bias2[i] = b2[i];
        else {
            int c = i - 64;
            float s = bc[c];
            for (int j = 0; j < 64; j++) s += Wc[c * 64 + j] * b2[j];
            bias2[i] = s;
        }
    }
}

// x fp32 -> A1 bf16 x-zone + zeroed pad (pedges aliases A1u — Inf/NaN hazard)
//        -> X8 fp8 rows (32 B: 24 real + 8 zero pad)
__global__ __launch_bounds__(256) void k_castx(const float* __restrict__ x,
                                               unsigned int* __restrict__ A1u,
                                               unsigned short* __restrict__ X8s) {
    int gid = blockIdx.x * 256 + threadIdx.x;
    if (gid >= N_NODES * 16) return;
    int n = gid >> 4, kp = gid & 15;
    if (kp < 12) {
        const float2 v = *(const float2*)(x + n * 24 + kp * 2);
        A1u[n * 32 + kp] = (unsigned int)f2bf(v.x) | ((unsigned int)f2bf(v.y) << 16);
        X8s[n * 16 + kp] = pk_fp8(v.x, v.y);
    } else {
        int p = kp - 12;
        uint2 z; z.x = 0u; z.y = 0u;
        *(uint2*)(A1u + n * 32 + 24 + p * 2) = z;
        X8s[n * 16 + kp] = 0;
    }
}

// ---------------- aggregations (fp8 gather tables) ----------------

// agg1: gather 32B X8 rows, 4 lanes/edge (uint2 = 8 fp8), 32 edges/iter
__global__ __launch_bounds__(256) void k_agg1(const unsigned int* __restrict__ X8u,
                                              const int* __restrict__ rowptr,
                                              const int* __restrict__ srcs,
                                              unsigned int* __restrict__ A1w, int N) {
    int node = (blockIdx.x * 256 + threadIdx.x) >> 6;
    int lane = threadIdx.x & 63;
    if (node >= N) return;
    int b = rowptr[node], e = rowptr[node + 1];
    int grp = lane >> 2;    // 0..15 edge slot
    int sub = lane & 3;     // 8B chunk of 32B row (channels sub*8..+7)
    const unsigned int* basep = X8u + sub * 2;
    float2v A[4] = {{0.f, 0.f}, {0.f, 0.f}, {0.f, 0.f}, {0.f, 0.f}};
    int nfull = (e - b) & ~31;
    int j = b;
    for (; j < b + nfull; j += 32) {
        int s0 = srcs[j + grp];
        int s1 = srcs[j + 16 + grp];
        uint2 u0 = *(const uint2*)(basep + (size_t)s0 * 8);
        uint2 u1 = *(const uint2*)(basep + (size_t)s1 * 8);
        accum8(A, u0);
        accum8(A, u1);
    }
    if (j < e) {
        int j0 = j + grp, j1 = j0 + 16;
        int s0 = srcs[j0], s1 = srcs[j1];
        uint2 u0 = *(const uint2*)(basep + (size_t)s0 * 8);
        uint2 u1 = *(const uint2*)(basep + (size_t)s1 * 8);
        if (j0 >= e) { u0.x = 0; u0.y = 0; }
        if (j1 >= e) { u1.x = 0; u1.y = 0; }
        accum8(A, u0);
        accum8(A, u1);
    }
#pragma unroll
    for (int m = 4; m <= 32; m <<= 1) {
#pragma unroll
        for (int q = 0; q < 4; q++) {
            A[q].x += __shfl_xor(A[q].x, m, 64);
            A[q].y += __shfl_xor(A[q].y, m, 64);
        }
    }
    if (lane < 4) {
        // sub==3 holds sums of X8 pad bytes (zeros) -> writes zeros to pad dwords 24..27
        float inv = 1.f / (float)max(e - b, 1);
        uint4 o;
        o.x = (unsigned int)f2bf(A[0].x * inv) | ((unsigned int)f2bf(A[0].y * inv) << 16);
        o.y = (unsigned int)f2bf(A[1].x * inv) | ((unsigned int)f2bf(A[1].y * inv) << 16);
        o.z = (unsigned int)f2bf(A[2].x * inv) | ((unsigned int)f2bf(A[2].y * inv) << 16);
        o.w = (unsigned int)f2bf(A[3].x * inv) | ((unsigned int)f2bf(A[3].y * inv) << 16);
        *(uint4*)(A1w + (size_t)node * 32 + 12 + sub * 4) = o;
    }
}

// agg2: gather 64B H8 rows, 8 lanes/edge (uint2 = 8 fp8), 32 edges/iter
__global__ __launch_bounds__(256) void k_agg2(const unsigned int* __restrict__ H8u,
                                              const int* __restrict__ rowptr,
                                              const int* __restrict__ srcs,
                                              unsigned int* __restrict__ A2w, int N) {
    int node = (blockIdx.x * 256 + threadIdx.x) >> 6;
    int lane = threadIdx.x & 63;
    if (node >= N) return;
    int b = rowptr[node], e = rowptr[node + 1];
    int grp = lane >> 3;    // 0..7 edge slot
    int sub = lane & 7;     // 8B chunk of 64B row (channels sub*8..+7)
    const unsigned int* basep = H8u + sub * 2;
    float2v A[4] = {{0.f, 0.f}, {0.f, 0.f}, {0.f, 0.f}, {0.f, 0.f}};
    int nfull = (e - b) & ~31;
    int j = b;
    for (; j < b + nfull; j += 32) {
        int s0 = srcs[j + grp];
        int s1 = srcs[j + 8 + grp];
        int s2 = srcs[j + 16 + grp];
        int s3 = srcs[j + 24 + grp];
        uint2 u0 = *(const uint2*)(basep + (size_t)s0 * 16);
        uint2 u1 = *(const uint2*)(basep + (size_t)s1 * 16);
        uint2 u2 = *(const uint2*)(basep + (size_t)s2 * 16);
        uint2 u3 = *(const uint2*)(basep + (size_t)s3 * 16);
        accum8(A, u0);
        accum8(A, u1);
        accum8(A, u2);
        accum8(A, u3);
    }
    if (j < e) {
        int j0 = j + grp, j1 = j0 + 8, j2 = j0 + 16, j3 = j0 + 24;
        int s0 = srcs[j0], s1 = srcs[j1], s2 = srcs[j2], s3 = srcs[j3];
        uint2 u0 = *(const uint2*)(basep + (size_t)s0 * 16);
        uint2 u1 = *(const uint2*)(basep + (size_t)s1 * 16);
        uint2 u2 = *(const uint2*)(basep + (size_t)s2 * 16);
        uint2 u3 = *(const uint2*)(basep + (size_t)s3 * 16);
        if (j0 >= e) { u0.x = 0; u0.y = 0; }
        if (j1 >= e) { u1.x = 0; u1.y = 0; }
        if (j2 >= e) { u2.x = 0; u2.y = 0; }
        if (j3 >= e) { u3.x = 0; u3.y = 0; }
        accum8(A, u0);
        accum8(A, u1);
        accum8(A, u2);
        accum8(A, u3);
    }
#pragma unroll
    for (int m = 8; m <= 32; m <<= 1) {
#pragma unroll
        for (int q = 0; q < 4; q++) {
            A[q].x += __shfl_xor(A[q].x, m, 64);
            A[q].y += __shfl_xor(A[q].y, m, 64);
        }
    }
    if (lane < 8) {
        float inv = 1.f / (float)max(e - b, 1);
        uint4 o;
        o.x = (unsigned int)f2bf(A[0].x * inv) | ((unsigned int)f2bf(A[0].y * inv) << 16);
        o.y = (unsigned int)f2bf(A[1].x * inv) | ((unsigned int)f2bf(A[1].y * inv) << 16);
        o.z = (unsigned int)f2bf(A[2].x * inv) | ((unsigned int)f2bf(A[2].y * inv) << 16);
        o.w = (unsigned int)f2bf(A[3].x * inv) | ((unsigned int)f2bf(A[3].y * inv) << 16);
        *(uint4*)(A2w + (size_t)node * 64 + sub * 4) = o;
    }
}

// ---------------- MFMA GEMMs (no LDS; B^T in registers) ----------------

// h = relu(A1 @ Bt1^T + b1): bf16 into A2 h-half AND fp8 into H8
__global__ __launch_bounds__(256) void k_gemm1(const unsigned short* __restrict__ A1,
                                               const unsigned short* __restrict__ Bt1,
                                               const float* __restrict__ b1,
                                               unsigned short* __restrict__ A2s,
                                               unsigned char* __restrict__ H8b) {
    int wave = (blockIdx.x * 256 + threadIdx.x) >> 6;
    int lane = threadIdx.x & 63;
    int m = lane & 15, quad = lane >> 4;
    if (wave >= NSTRIPS) return;
    short8 bf[4][2];
#pragma unroll
    for (int t = 0; t < 4; t++)
#pragma unroll
        for (int s = 0; s < 2; s++)
            bf[t][s] = *(const short8*)(Bt1 + (t * 16 + m) * 64 + s * 32 + quad * 8);
    float bias[4];
#pragma unroll
    for (int t = 0; t < 4; t++) bias[t] = b1[t * 16 + m];

    int row0 = wave * 16;
    short8 a0 = *(const short8*)(A1 + (row0 + m) * 64 + quad * 8);
    short8 a1 = *(const short8*)(A1 + (row0 + m) * 64 + 32 + quad * 8);
    float4_ acc[4];
#pragma unroll
    for (int t = 0; t < 4; t++) {
        float4_ c = {0.f, 0.f, 0.f, 0.f};
        c = __builtin_amdgcn_mfma_f32_16x16x32_bf16(a0, bf[t][0], c, 0, 0, 0);
        c = __builtin_amdgcn_mfma_f32_16x16x32_bf16(a1, bf[t][1], c, 0, 0, 0);
        acc[t] = c;
    }
#pragma unroll
    for (int t = 0; t < 4; t++) {
        int col = t * 16 + m;
#pragma unroll
        for (int r = 0; r < 4; r++) {
            int row = row0 + quad * 4 + r;
            float v = fmaxf(acc[t][r] + bias[t], 0.f);
            A2s[row * 128 + 64 + col] = f2bf(v);
            H8b[row * 64 + col] =
                (unsigned char)(__builtin_amdgcn_cvt_pk_fp8_f32(v, 0.f, 0, false) & 0xFF);
        }
    }
}

__global__ __launch_bounds__(256) void k_gemm2(const unsigned short* __restrict__ Bt2,
                                               const float* __restrict__ bias2,
                                               unsigned short* A2s,
                                               float* logits) {
    int wave = (blockIdx.x * 256 + threadIdx.x) >> 6;
    int lane = threadIdx.x & 63;
    int m = lane & 15, quad = lane >> 4;
    if (wave >= NSTRIPS) return;
    short8 bf[5][4];
#pragma unroll
    for (int t = 0; t < 5; t++)
#pragma unroll
        for (int s = 0; s < 4; s++)
            bf[t][s] = *(const short8*)(Bt2 + (t * 16 + m) * 128 + s * 32 + quad * 8);
    float bias[5];
#pragma unroll
    for (int t = 0; t < 5; t++) bias[t] = bias2[t * 16 + m];

    int row0 = wave * 16;
    short8 a[4];
#pragma unroll
    for (int s = 0; s < 4; s++)
        a[s] = *(const short8*)(A2s + (row0 + m) * 128 + s * 32 + quad * 8);
    float4_ acc[5];
#pragma unroll
    for (int t = 0; t < 5; t++) {
        float4_ c = {0.f, 0.f, 0.f, 0.f};
#pragma unroll
        for (int s = 0; s < 4; s++)
            c = __builtin_amdgcn_mfma_f32_16x16x32_bf16(a[s], bf[t][s], c, 0, 0, 0);
        acc[t] = c;
    }
    float* embp = (float*)A2s;
#pragma unroll
    for (int t = 0; t < 4; t++) {
#pragma unroll
        for (int r = 0; r < 4; r++) {
            int row = row0 + quad * 4 + r;
            embp[row * 64 + t * 16 + m] = acc[t][r] + bias[t];
        }
    }
#pragma unroll
    for (int r = 0; r < 4; r++) {
        int row = row0 + quad * 4 + r;
        logits[row * 16 + m] = acc[4][r] + bias[4];
    }
}

// ---------------- launch ----------------

extern "C" void kernel_launch(void* const* d_in, const int* in_sizes, int n_in,
                              void* d_out, int out_size, void* d_ws, size_t ws_size,
                              hipStream_t stream) {
    const float* x = (const float*)d_in[0];
    const int* edge = (const int*)d_in[1];
    const int* srcIdx = edge;
    const int* dstIdx = edge + N_EDGES;
    const float* W1l = (const float*)d_in[2];
    const float* b1  = (const float*)d_in[3];
    const float* W1r = (const float*)d_in[4];
    const float* W2l = (const float*)d_in[5];
    const float* b2  = (const float*)d_in[6];
    const float* W2r = (const float*)d_in[7];
    const float* Wc  = (const float*)d_in[8];
    const float* bc  = (const float*)d_in[9];

    float* logits = (float*)d_out;
    unsigned short* A2s = (unsigned short*)((float*)d_out + (size_t)N_NODES * N_CLASSES);
    unsigned int* A2u = (unsigned int*)A2s;

    char* w = (char*)d_ws;
    auto carve = [&](size_t bytes) {
        char* p = w;
        w += (bytes + 255) & ~(size_t)255;
        return p;
    };
    int* rowptr          = (int*)carve((N_NODES + 1) * sizeof(int));
    int* srcs            = (int*)carve((size_t)(N_EDGES + 32) * sizeof(int));
    unsigned int* A1u    = (unsigned int*)carve((size_t)N_NODES * 32 * sizeof(unsigned int));
    unsigned short* X8s  = (unsigned short*)carve((size_t)N_NODES * 32);   // fp8 x, 32B rows
    unsigned char* H8b   = (unsigned char*)carve((size_t)N_NODES * 64);    // fp8 h, 64B rows
    int* bucketCnt       = (int*)carve(NBUCK * sizeof(int));
    int* bucketBase      = (int*)carve((NBUCK + 1) * sizeof(int));
    int* bucketFill      = (int*)carve(NBUCK * sizeof(int));
    unsigned short* Bt1  = (unsigned short*)carve(64 * 64 * sizeof(unsigned short));
    unsigned short* Bt2  = (unsigned short*)carve(80 * 128 * sizeof(unsigned short));
    float* bias2         = (float*)carve(80 * sizeof(float));

    unsigned int* pedges = A1u;   // consumed by k_bucket before k_castx writes A1
    unsigned short* A1s = (unsigned short*)A1u;
    unsigned int* X8u = (unsigned int*)X8s;
    unsigned int* H8u = (unsigned int*)H8b;

    k_prep<<<1, 256, 0, stream>>>(W1l, W1r, W2l, W2r, Wc, b2, bc, Bt1, Bt2, bias2);

    hipMemsetAsync(bucketCnt, 0, NBUCK * sizeof(int), stream);
    k_phist<<<NCHUNK, 1024, 0, stream>>>(dstIdx, bucketCnt);
    k_scanb<<<1, 1024, 0, stream>>>(bucketCnt, bucketBase, bucketFill, srcs, N_EDGES);
    k_part<<<NCHUNK, 1024, 0, stream>>>(srcIdx, dstIdx, bucketFill, pedges);
    k_bucket<<<NBUCK, 1024, 0, stream>>>(pedges, bucketBase, rowptr, srcs,
                                         N_NODES, N_EDGES);

    k_castx<<<(N_NODES * 16 + 255) / 256, 256, 0, stream>>>(x, A1u, X8s);
    k_agg1<<<(N_NODES * 64 + 255) / 256, 256, 0, stream>>>(X8u, rowptr, srcs, A1u, N_NODES);
    k_gemm1<<<(NSTRIPS + 3) / 4, 256, 0, stream>>>(A1s, Bt1, b1, A2s, H8b);
    k_agg2<<<(N_NODES * 64 + 255) / 256, 256, 0, stream>>>(H8u, rowptr, srcs, A2u, N_NODES);
    k_gemm2<<<(NSTRIPS + 3) / 4, 256, 0, stream>>>(Bt2, bias2, A2s, logits);
}